// Round 1
// baseline (4289.602 us; speedup 1.0000x reference)
//
#include <hip/hip_runtime.h>

#define N_NODES 10000
#define N_EDGES 320000

// scales
#define SC_W1      0.17677669529663687f   // 1/sqrt(32)
#define SC_MLP1    0.35355339059327373f   // 1/sqrt(8)
#define SC_MLP2    0.125f                 // 1/sqrt(64)
#define SC_EDGE    0.125f                 // INV_SQRT2 / sqrt(NUM_NEIGHBORS=32)
#define INV_SQRT3  0.5773502691896258f
#define COS_MIX    0.9238795325112867f    // cos(pi/8)
#define SIN_CONV   0.04783542904563623f   // sin(pi/8) * (1/sqrt(64))

// ws layout (in floats)
#define WS_WT1   0        // [64][8]    = 512
#define WS_WT2   512      // [64][64]   = 4096
#define WS_WTP   4608     // [32][4][64]= 8192
#define WS_FEAT0 12800    // [N][32]
#define WS_FEAT1 332800   // [N][96]
#define WS_SELF0 1292800  // [N][32]
#define WS_SELF1 1612800  // [N][96]
#define WS_N0    2572800  // [N][64]
#define WS_N1    3212800  // [N][192]

__device__ __forceinline__ float gelu_tanh(float x) {
    // jax.nn.gelu default (approximate=True)
    float x3 = x * x * x;
    float t = tanhf(0.7978845608028654f * (x + 0.044715f * x3));
    return 0.5f * x * (1.0f + t);
}

__global__ void prep_weights(const float* __restrict__ Wm1, const float* __restrict__ Wm2,
                             const float* __restrict__ Wp00, const float* __restrict__ Wp01,
                             const float* __restrict__ Wp10, const float* __restrict__ Wp11,
                             float* __restrict__ ws) {
    int gid = blockIdx.x * blockDim.x + threadIdx.x;
    if (gid < 512) {          // Wt1[j][k] = Wm1[k][j], (8x64) -> (64x8)
        int j = gid >> 3, k = gid & 7;
        ws[WS_WT1 + gid] = Wm1[k * 64 + j];
    }
    if (gid < 4096) {         // Wt2[j][k] = Wm2[k][j], (64x64)
        int j = gid >> 6, k = gid & 63;
        ws[WS_WT2 + gid] = Wm2[k * 64 + j];
    }
    if (gid < 8192) {         // Wtp[u][m][k] = Wp_m[k][u], (64x32) each
        int u = gid >> 8, m = (gid >> 6) & 3, k = gid & 63;
        const float* W = (m == 0) ? Wp00 : (m == 1) ? Wp01 : (m == 2) ? Wp10 : Wp11;
        ws[WS_WTP + gid] = W[k * 32 + u];
    }
}

__global__ void node_transform(const float* __restrict__ x,
                               const float* __restrict__ W1_0e,
                               const float* __restrict__ W1_1o,
                               float* __restrict__ ws) {
    int gid = blockIdx.x * blockDim.x + threadIdx.x;
    int n = gid >> 6, w = gid & 63;
    if (n >= N_NODES) return;
    const float* xr = x + n * 128;
    float f0 = 0.f, f1x = 0.f, f1y = 0.f, f1z = 0.f;
#pragma unroll
    for (int u = 0; u < 32; ++u) {
        float w0 = W1_0e[u * 64 + w];
        float w1 = W1_1o[u * 64 + w];
        f0  += xr[u] * w0;
        f1x += xr[32 + u * 3 + 0] * w1;
        f1y += xr[32 + u * 3 + 1] * w1;
        f1z += xr[32 + u * 3 + 2] * w1;
    }
    f0 *= SC_W1; f1x *= SC_W1; f1y *= SC_W1; f1z *= SC_W1;
    if (w < 32) {
        ws[WS_FEAT0 + n * 32 + w] = f0;
        ws[WS_FEAT1 + n * 96 + w * 3 + 0] = f1x;
        ws[WS_FEAT1 + n * 96 + w * 3 + 1] = f1y;
        ws[WS_FEAT1 + n * 96 + w * 3 + 2] = f1z;
    } else {
        int ww = w - 32;
        ws[WS_SELF0 + n * 32 + ww] = f0;
        ws[WS_SELF1 + n * 96 + ww * 3 + 0] = f1x;
        ws[WS_SELF1 + n * 96 + ww * 3 + 1] = f1y;
        ws[WS_SELF1 + n * 96 + ww * 3 + 2] = f1z;
    }
}

__global__ __launch_bounds__(256) void edge_kernel(
        const float* __restrict__ edge_attr, const float* __restrict__ edge_scalar,
        const int* __restrict__ edge_src, const int* __restrict__ edge_dst,
        const float* __restrict__ ws_ro, float* __restrict__ ws_rw) {
    int e = blockIdx.x * blockDim.x + threadIdx.x;
    if (e >= N_EDGES) return;
    int src = edge_src[e];
    int dst = edge_dst[e];

    const float* Wt1 = ws_ro + WS_WT1;
    const float* Wt2 = ws_ro + WS_WT2;
    const float* Wtp = ws_ro + WS_WTP;

    float4 es0 = *(const float4*)(edge_scalar + e * 8);
    float4 es1 = *(const float4*)(edge_scalar + e * 8 + 4);
    float es[8] = {es0.x, es0.y, es0.z, es0.w, es1.x, es1.y, es1.z, es1.w};
    float4 ea  = *(const float4*)(edge_attr + e * 4);   // ea.x = ea0, ea.yzw = ea1

    float h1[64];
#pragma unroll
    for (int j = 0; j < 64; ++j) {
        float s = 0.f;
#pragma unroll
        for (int k = 0; k < 8; ++k) s += es[k] * Wt1[j * 8 + k];
        h1[j] = gelu_tanh(s * SC_MLP1);
    }
    float h2[64];
#pragma unroll
    for (int j = 0; j < 64; ++j) {
        float s = 0.f;
#pragma unroll
        for (int k = 0; k < 64; ++k) s += h1[k] * Wt2[j * 64 + k];
        h2[j] = gelu_tanh(s * SC_MLP2);
    }

    const float* f0p = ws_ro + WS_FEAT0 + src * 32;
    const float* f1p = ws_ro + WS_FEAT1 + src * 96;
    float* n0p = ws_rw + WS_N0 + dst * 64;
    float* n1p = ws_rw + WS_N1 + dst * 192;

    for (int u = 0; u < 32; ++u) {
        const float* wp = Wtp + u * 256;
        float w00 = 0.f, w01 = 0.f, w10 = 0.f, w11 = 0.f;
#pragma unroll
        for (int k = 0; k < 64; ++k) {
            float h = h2[k];
            w00 += h * wp[k];
            w01 += h * wp[64 + k];
            w10 += h * wp[128 + k];
            w11 += h * wp[192 + k];
        }
        float e0u = f0p[u];
        float e1x = f1p[u * 3 + 0];
        float e1y = f1p[u * 3 + 1];
        float e1z = f1p[u * 3 + 2];

        float out0a = w00 * e0u * ea.x * SC_EDGE;
        float dotp  = e1x * ea.y + e1y * ea.z + e1z * ea.w;
        float out0b = w11 * dotp * (INV_SQRT3 * SC_EDGE);
        float t01   = w01 * e0u * SC_EDGE;
        float t10   = w10 * ea.x * SC_EDGE;

        atomicAdd(n0p + u,        out0a);
        atomicAdd(n0p + 32 + u,   out0b);
        atomicAdd(n1p + u * 3 + 0, t01 * ea.y);
        atomicAdd(n1p + u * 3 + 1, t01 * ea.z);
        atomicAdd(n1p + u * 3 + 2, t01 * ea.w);
        atomicAdd(n1p + 96 + u * 3 + 0, t10 * e1x);
        atomicAdd(n1p + 96 + u * 3 + 1, t10 * e1y);
        atomicAdd(n1p + 96 + u * 3 + 2, t10 * e1z);
    }
}

__global__ void finalize(const float* __restrict__ ws,
                         const float* __restrict__ W2_0e,
                         const float* __restrict__ W2_1o,
                         float* __restrict__ out) {
    int gid = blockIdx.x * blockDim.x + threadIdx.x;
    int n = gid >> 5, wp = gid & 31;
    if (n >= N_NODES) return;
    const float* n0p = ws + WS_N0 + n * 64;
    const float* n1p = ws + WS_N1 + n * 192;
    float c0 = 0.f, c1x = 0.f, c1y = 0.f, c1z = 0.f;
#pragma unroll
    for (int w = 0; w < 64; ++w) {
        float a = W2_0e[w * 32 + wp];
        float b = W2_1o[w * 32 + wp];
        c0  += n0p[w] * a;
        c1x += n1p[w * 3 + 0] * b;
        c1y += n1p[w * 3 + 1] * b;
        c1z += n1p[w * 3 + 2] * b;
    }
    float y0  = COS_MIX * ws[WS_SELF0 + n * 32 + wp] + SIN_CONV * c0;
    float y1x = COS_MIX * ws[WS_SELF1 + n * 96 + wp * 3 + 0] + SIN_CONV * c1x;
    float y1y = COS_MIX * ws[WS_SELF1 + n * 96 + wp * 3 + 1] + SIN_CONV * c1y;
    float y1z = COS_MIX * ws[WS_SELF1 + n * 96 + wp * 3 + 2] + SIN_CONV * c1z;
    out[n * 128 + wp] = y0;
    out[n * 128 + 32 + wp * 3 + 0] = y1x;
    out[n * 128 + 32 + wp * 3 + 1] = y1y;
    out[n * 128 + 32 + wp * 3 + 2] = y1z;
}

extern "C" void kernel_launch(void* const* d_in, const int* in_sizes, int n_in,
                              void* d_out, int out_size, void* d_ws, size_t ws_size,
                              hipStream_t stream) {
    const float* node_input  = (const float*)d_in[0];
    const float* edge_attr   = (const float*)d_in[1];
    const float* edge_scalar = (const float*)d_in[2];
    const float* W1_0e       = (const float*)d_in[3];
    const float* W1_1o       = (const float*)d_in[4];
    const float* W_mlp1      = (const float*)d_in[5];
    const float* W_mlp2      = (const float*)d_in[6];
    const float* Wp00        = (const float*)d_in[7];
    const float* Wp01        = (const float*)d_in[8];
    const float* Wp10        = (const float*)d_in[9];
    const float* Wp11        = (const float*)d_in[10];
    const float* W2_0e       = (const float*)d_in[11];
    const float* W2_1o       = (const float*)d_in[12];
    const int*   edge_src    = (const int*)d_in[13];
    const int*   edge_dst    = (const int*)d_in[14];
    float* ws = (float*)d_ws;
    float* outp = (float*)d_out;

    // zero the n0/n1 accumulators (atomics accumulate into them)
    hipMemsetAsync(ws + WS_N0, 0, (640000 + 1920000) * sizeof(float), stream);

    prep_weights<<<32, 256, 0, stream>>>(W_mlp1, W_mlp2, Wp00, Wp01, Wp10, Wp11, ws);
    node_transform<<<(N_NODES * 64 + 255) / 256, 256, 0, stream>>>(node_input, W1_0e, W1_1o, ws);
    edge_kernel<<<(N_EDGES + 255) / 256, 256, 0, stream>>>(edge_attr, edge_scalar,
                                                           edge_src, edge_dst, ws, ws);
    finalize<<<(N_NODES * 32 + 255) / 256, 256, 0, stream>>>(ws, W2_0e, W2_1o, outp);
}

// Round 2
// 672.548 us; speedup vs baseline: 6.3781x; 6.3781x over previous
//
#include <hip/hip_runtime.h>

typedef unsigned int uint32;
typedef unsigned short ushort16;

#define N_NODES 10000
#define N_EDGES 320000

// scales
#define SC_W1      0.17677669529663687f   // 1/sqrt(32)
#define SC_MLP1    0.35355339059327373f   // 1/sqrt(8)
#define SC_MLP2    0.125f                 // 1/sqrt(64)
#define SC_EDGE    0.125f                 // INV_SQRT2 / sqrt(NUM_NEIGHBORS=32)
#define INV_SQRT3  0.5773502691896258f
#define COS_MIX    0.9238795325112867f    // cos(pi/8)
#define SIN_CONV   0.04783542904563623f   // sin(pi/8) / sqrt(64)

// ws layout: float indices
#define WS_WT1   0        // [64][8]
#define WS_WT2   512      // [64][64]
#define WS_WTP   4608     // [32][4][64]
#define WS_FEAT0 12800    // [N][32]
#define WS_FEAT1 332800   // [N][96]
#define WS_SELF0 1292800  // [N][32]
#define WS_SELF1 1612800  // [N][96]
// int indices (on (int*)ws)
#define I_CNT    2572800  // [N+1]
#define I_OFF    2582816  // [N+1]
#define I_CUR    2592832  // [N]
#define I_ORD    2602848  // [E]
// uint indices (on (uint*)ws): packed bf16 w-pairs, [E][64]
#define U_WBUF   2922880  // 320000*64 uints = 82 MB

__device__ __forceinline__ float gelu_tanh(float x) {
    float x3 = x * x * x;
    float t = tanhf(0.7978845608028654f * (x + 0.044715f * x3));
    return 0.5f * x * (1.0f + t);
}

__device__ __forceinline__ uint32 f2bf(float x) {
    uint32 u = __float_as_uint(x);
    return (u + 0x7fffu + ((u >> 16) & 1u)) >> 16;   // RNE, no NaN handling needed
}
__device__ __forceinline__ uint32 pack_bf2(float a, float b) {
    return f2bf(a) | (f2bf(b) << 16);
}

__global__ void prep_weights(const float* __restrict__ Wm1, const float* __restrict__ Wm2,
                             const float* __restrict__ Wp00, const float* __restrict__ Wp01,
                             const float* __restrict__ Wp10, const float* __restrict__ Wp11,
                             float* __restrict__ ws) {
    int gid = blockIdx.x * blockDim.x + threadIdx.x;
    if (gid < 512) {          // Wt1[j][k] = Wm1[k][j]
        int j = gid >> 3, k = gid & 7;
        ws[WS_WT1 + gid] = Wm1[k * 64 + j];
    }
    if (gid < 4096) {         // Wt2[j][k] = Wm2[k][j]
        int j = gid >> 6, k = gid & 63;
        ws[WS_WT2 + gid] = Wm2[k * 64 + j];
    }
    if (gid < 8192) {         // Wtp[u][m][k] = Wp_m[k][u]
        int u = gid >> 8, m = (gid >> 6) & 3, k = gid & 63;
        const float* W = (m == 0) ? Wp00 : (m == 1) ? Wp01 : (m == 2) ? Wp10 : Wp11;
        ws[WS_WTP + gid] = W[k * 32 + u];
    }
}

__global__ void node_transform(const float* __restrict__ x,
                               const float* __restrict__ W1_0e,
                               const float* __restrict__ W1_1o,
                               float* __restrict__ ws) {
    int gid = blockIdx.x * blockDim.x + threadIdx.x;
    int n = gid >> 6, w = gid & 63;
    if (n >= N_NODES) return;
    const float* xr = x + n * 128;
    float f0 = 0.f, f1x = 0.f, f1y = 0.f, f1z = 0.f;
#pragma unroll
    for (int u = 0; u < 32; ++u) {
        float w0 = W1_0e[u * 64 + w];
        float w1 = W1_1o[u * 64 + w];
        f0  += xr[u] * w0;
        f1x += xr[32 + u * 3 + 0] * w1;
        f1y += xr[32 + u * 3 + 1] * w1;
        f1z += xr[32 + u * 3 + 2] * w1;
    }
    f0 *= SC_W1; f1x *= SC_W1; f1y *= SC_W1; f1z *= SC_W1;
    if (w < 32) {
        ws[WS_FEAT0 + n * 32 + w] = f0;
        ws[WS_FEAT1 + n * 96 + w * 3 + 0] = f1x;
        ws[WS_FEAT1 + n * 96 + w * 3 + 1] = f1y;
        ws[WS_FEAT1 + n * 96 + w * 3 + 2] = f1z;
    } else {
        int ww = w - 32;
        ws[WS_SELF0 + n * 32 + ww] = f0;
        ws[WS_SELF1 + n * 96 + ww * 3 + 0] = f1x;
        ws[WS_SELF1 + n * 96 + ww * 3 + 1] = f1y;
        ws[WS_SELF1 + n * 96 + ww * 3 + 2] = f1z;
    }
}

// ---- CSR build ----
__global__ void csr_count(const int* __restrict__ dst, int* __restrict__ cnt) {
    int e = blockIdx.x * blockDim.x + threadIdx.x;
    if (e < N_EDGES) atomicAdd(&cnt[dst[e]], 1);
}

__global__ __launch_bounds__(256) void csr_scan(const int* __restrict__ cnt,
                                                int* __restrict__ off,
                                                int* __restrict__ cur) {
    __shared__ int partial[256];
    int t = threadIdx.x;
    const int CHUNK = 40;                      // 256*40 = 10240 >= 10000
    int base = t * CHUNK;
    int s = 0;
#pragma unroll
    for (int j = 0; j < CHUNK; ++j) {
        int idx = base + j;
        s += (idx < N_NODES) ? cnt[idx] : 0;
    }
    partial[t] = s;
    __syncthreads();
    for (int o = 1; o < 256; o <<= 1) {
        int v = partial[t];
        int add = (t >= o) ? partial[t - o] : 0;
        __syncthreads();
        partial[t] = v + add;
        __syncthreads();
    }
    int run = (t > 0) ? partial[t - 1] : 0;    // exclusive prefix of this chunk
    for (int j = 0; j < CHUNK; ++j) {
        int idx = base + j;
        if (idx < N_NODES) {
            off[idx] = run;
            cur[idx] = run;
            run += cnt[idx];
        }
    }
    if (t == 255) off[N_NODES] = run;
}

__global__ void csr_scatter(const int* __restrict__ dst, int* __restrict__ cur,
                            int* __restrict__ ord) {
    int e = blockIdx.x * blockDim.x + threadIdx.x;
    if (e < N_EDGES) {
        int pos = atomicAdd(&cur[dst[e]], 1);
        ord[pos] = e;
    }
}

// ---- Phase A: per-edge MLP -> packed bf16 tensor-product coefficients ----
__global__ __launch_bounds__(256) void edge_mlp(const float* __restrict__ edge_scalar,
                                                const float* __restrict__ ws_ro,
                                                uint32* __restrict__ wbuf) {
    int e = blockIdx.x * blockDim.x + threadIdx.x;
    if (e >= N_EDGES) return;

    const float* Wt1 = ws_ro + WS_WT1;
    const float* Wt2 = ws_ro + WS_WT2;
    const float* Wtp = ws_ro + WS_WTP;

    float4 es0 = *(const float4*)(edge_scalar + (size_t)e * 8);
    float4 es1 = *(const float4*)(edge_scalar + (size_t)e * 8 + 4);
    float es[8] = {es0.x, es0.y, es0.z, es0.w, es1.x, es1.y, es1.z, es1.w};

    float h1[64];
#pragma unroll
    for (int j = 0; j < 64; ++j) {
        float s = 0.f;
#pragma unroll
        for (int k = 0; k < 8; ++k) s += es[k] * Wt1[j * 8 + k];
        h1[j] = gelu_tanh(s * SC_MLP1);
    }
    float h2[64];
#pragma unroll
    for (int j = 0; j < 64; ++j) {
        float s = 0.f;
#pragma unroll
        for (int k = 0; k < 64; ++k) s += h1[k] * Wt2[j * 64 + k];
        h2[j] = gelu_tanh(s * SC_MLP2);
    }

    uint32* wout = wbuf + (size_t)e * 64;
    for (int u = 0; u < 32; ++u) {
        const float* wp = Wtp + u * 256;
        float w00 = 0.f, w01 = 0.f, w10 = 0.f, w11 = 0.f;
#pragma unroll
        for (int k = 0; k < 64; ++k) {
            float h = h2[k];
            w00 += h * wp[k];
            w01 += h * wp[64 + k];
            w10 += h * wp[128 + k];
            w11 += h * wp[192 + k];
        }
        // fold edge-level scales
        w00 *= SC_EDGE;
        w01 *= SC_EDGE;
        w10 *= SC_EDGE;
        w11 *= SC_EDGE * INV_SQRT3;
        wout[u]      = pack_bf2(w00, w01);   // half0 pair
        wout[32 + u] = pack_bf2(w10, w11);   // half1 pair
    }
}

// ---- Phase B: wave-per-node gather + reduce + W2 + mix ----
__global__ __launch_bounds__(256) void gather(const int* __restrict__ off,
                                              const int* __restrict__ ord,
                                              const int* __restrict__ esrc,
                                              const float* __restrict__ edge_attr,
                                              const uint32* __restrict__ wbuf,
                                              const float* __restrict__ ws_ro,
                                              const float* __restrict__ W2_0e,
                                              const float* __restrict__ W2_1o,
                                              float* __restrict__ out) {
    int wv = __builtin_amdgcn_readfirstlane((int)(threadIdx.x >> 6));
    int lane = threadIdx.x & 63;
    int node = blockIdx.x * 4 + wv;           // grid = 2500, exact: no OOB
    int u = lane & 31;
    int half = lane >> 5;

    const float* feat0 = ws_ro + WS_FEAT0;
    const float* feat1 = ws_ro + WS_FEAT1;

    int beg = off[node];
    int end = off[node + 1];

    float a0 = 0.f, a1x = 0.f, a1y = 0.f, a1z = 0.f;

#pragma unroll 2
    for (int i = beg; i < end; ++i) {
        int e = ord[i];                       // wave-uniform
        int src = esrc[e];                    // wave-uniform
        float4 ea = *(const float4*)(edge_attr + (size_t)e * 4);
        uint32 wvv = wbuf[(size_t)e * 64 + (half << 5) + u];
        float wa = __uint_as_float(wvv << 16);
        float wb = __uint_as_float(wvv & 0xffff0000u);
        if (half == 0) {
            float e0 = feat0[src * 32 + u];
            a0  += wa * e0 * ea.x;            // w00'·e0·ea0
            float t = wb * e0;                // w01'·e0
            a1x += t * ea.y;
            a1y += t * ea.z;
            a1z += t * ea.w;
        } else {
            const float* f1 = feat1 + src * 96 + u * 3;
            float ex = f1[0], ey = f1[1], ez = f1[2];
            float d = ex * ea.y + ey * ea.z + ez * ea.w;
            a0  += wb * d;                    // w11''·dot
            float t = wa * ea.x;              // w10'·ea0
            a1x += t * ex;
            a1y += t * ey;
            a1z += t * ez;
        }
    }

    __shared__ float red[4][256];
    float* r = red[wv];
    int c = (half << 5) + u;
    r[c] = a0;                                // n0[64]
    int b = 64 + c * 3;                       // n1[64][3]
    r[b] = a1x; r[b + 1] = a1y; r[b + 2] = a1z;
    __syncthreads();

    if (half == 0) {
        float acc = 0.f;
#pragma unroll 8
        for (int w = 0; w < 64; ++w) acc += r[w] * W2_0e[w * 32 + u];
        out[node * 128 + u] = COS_MIX * ws_ro[WS_SELF0 + node * 32 + u] + SIN_CONV * acc;
    } else {
        float c0 = 0.f, c1 = 0.f, c2 = 0.f;
#pragma unroll 8
        for (int w = 0; w < 64; ++w) {
            float bw = W2_1o[w * 32 + u];
            c0 += r[64 + w * 3 + 0] * bw;
            c1 += r[64 + w * 3 + 1] * bw;
            c2 += r[64 + w * 3 + 2] * bw;
        }
        int o = node * 128 + 32 + u * 3;
        const float* s1 = ws_ro + WS_SELF1 + node * 96 + u * 3;
        out[o + 0] = COS_MIX * s1[0] + SIN_CONV * c0;
        out[o + 1] = COS_MIX * s1[1] + SIN_CONV * c1;
        out[o + 2] = COS_MIX * s1[2] + SIN_CONV * c2;
    }
}

extern "C" void kernel_launch(void* const* d_in, const int* in_sizes, int n_in,
                              void* d_out, int out_size, void* d_ws, size_t ws_size,
                              hipStream_t stream) {
    const float* node_input  = (const float*)d_in[0];
    const float* edge_attr   = (const float*)d_in[1];
    const float* edge_scalar = (const float*)d_in[2];
    const float* W1_0e       = (const float*)d_in[3];
    const float* W1_1o       = (const float*)d_in[4];
    const float* W_mlp1      = (const float*)d_in[5];
    const float* W_mlp2      = (const float*)d_in[6];
    const float* Wp00        = (const float*)d_in[7];
    const float* Wp01        = (const float*)d_in[8];
    const float* Wp10        = (const float*)d_in[9];
    const float* Wp11        = (const float*)d_in[10];
    const float* W2_0e       = (const float*)d_in[11];
    const float* W2_1o       = (const float*)d_in[12];
    const int*   edge_src    = (const int*)d_in[13];
    const int*   edge_dst    = (const int*)d_in[14];
    float* ws  = (float*)d_ws;
    int*   wsI = (int*)d_ws;
    uint32* wsU = (uint32*)d_ws;
    float* outp = (float*)d_out;

    hipMemsetAsync(wsI + I_CNT, 0, (N_NODES + 1) * sizeof(int), stream);

    prep_weights<<<32, 256, 0, stream>>>(W_mlp1, W_mlp2, Wp00, Wp01, Wp10, Wp11, ws);
    node_transform<<<(N_NODES * 64 + 255) / 256, 256, 0, stream>>>(node_input, W1_0e, W1_1o, ws);
    csr_count<<<(N_EDGES + 255) / 256, 256, 0, stream>>>(edge_dst, wsI + I_CNT);
    csr_scan<<<1, 256, 0, stream>>>(wsI + I_CNT, wsI + I_OFF, wsI + I_CUR);
    csr_scatter<<<(N_EDGES + 255) / 256, 256, 0, stream>>>(edge_dst, wsI + I_CUR, wsI + I_ORD);
    edge_mlp<<<(N_EDGES + 255) / 256, 256, 0, stream>>>(edge_scalar, ws, wsU + U_WBUF);
    gather<<<N_NODES / 4, 256, 0, stream>>>(wsI + I_OFF, wsI + I_ORD, edge_src, edge_attr,
                                            wsU + U_WBUF, ws, W2_0e, W2_1o, outp);
}

// Round 3
// 316.888 us; speedup vs baseline: 13.5366x; 2.1224x over previous
//
#include <hip/hip_runtime.h>

typedef unsigned int uint32;
typedef __attribute__((ext_vector_type(4))) float f32x4;
typedef __attribute__((ext_vector_type(8))) _Float16 halfx8;
typedef __attribute__((ext_vector_type(4))) uint32 uint32x4;

#define N_NODES 10000
#define N_EDGES 320000

// scales
#define SC_W1      0.17677669529663687f   // 1/sqrt(32)
#define SC_MLP1    0.35355339059327373f   // 1/sqrt(8)
#define SC_MLP2    0.125f                 // 1/sqrt(64)
#define INV_SQRT3  0.5773502691896258f
#define COS_MIX    0.9238795325112867f    // cos(pi/8)
#define SIN_CONV   0.04783542904563623f   // sin(pi/8) / sqrt(64)

// ws layout: float indices
#define WS_FEAT0 0        // [N][32]
#define WS_FEAT1 320000   // [N][96]
#define WS_SELF0 1280000  // [N][32]
#define WS_SELF1 1600000  // [N][96]
// int indices (on (int*)ws)
#define I_CNT    2560000  // [N+1]
#define I_OFF    2570016  // [N+1]
#define I_CUR    2580032  // [N]
#define I_ORD    2590048  // [E]
// uint indices (on (uint*)ws)
#define U_WF     2910048  // 28 frags x 64 lanes x 4 uints (f16 pairs)
#define U_WBUF   2917248  // [E][64] packed bf16 pairs

__device__ __forceinline__ uint32 f2bf(float x) {
    uint32 u = __float_as_uint(x);
    return (u + 0x7fffu + ((u >> 16) & 1u)) >> 16;
}
__device__ __forceinline__ uint32 pack_bf2(float a, float b) {
    return f2bf(a) | (f2bf(b) << 16);
}
__device__ __forceinline__ uint32 packh2(float a, float b) {
    _Float16 ha = (_Float16)a, hb = (_Float16)b;
    return (uint32)__builtin_bit_cast(unsigned short, ha) |
           ((uint32)__builtin_bit_cast(unsigned short, hb) << 16);
}
__device__ __forceinline__ unsigned short h16(float x) {
    _Float16 h = (_Float16)x;
    return __builtin_bit_cast(unsigned short, h);
}
// gelu(x) = x * sigmoid(1.5957x + 0.0713x^3)  (== tanh-approx gelu, branch-free)
__device__ __forceinline__ float gelu_fast(float x) {
    float x2 = x * x;
    float z = x * __builtin_fmaf(0.03567740814f, x2, 0.7978845608f);
    float E = __builtin_amdgcn_exp2f(z * -2.885390082f);   // exp(-2z)
    return x * __builtin_amdgcn_rcpf(1.0f + E);
}

// ---- prep: weight matrices -> per-lane MFMA B-fragments (f16) ----
// frag f: 0..3   = WB1[nt]          B[k][c]=Wm1[k][16nt+c15], k<8 else 0
//         4..11  = WB2[nt][ks]      B[k][c]=Wm2[32ks+kq+j][16nt+c15]
//         12..27 = WBP[nt][ks]      B[k][c]=Wp_m[k][u]*sc, c=16nt+c15, u=c&31, m=c>>5
__global__ void prep_frags(const float* __restrict__ Wm1, const float* __restrict__ Wm2,
                           const float* __restrict__ Wp00, const float* __restrict__ Wp01,
                           const float* __restrict__ Wp10, const float* __restrict__ Wp11,
                           uint32* __restrict__ wf) {
    int gid = blockIdx.x * blockDim.x + threadIdx.x;
    if (gid >= 28 * 64) return;
    int f = gid >> 6, lane = gid & 63;
    int kq = (lane >> 4) * 8;
    int c15 = lane & 15;
    float vals[8];
    if (f < 4) {
        int c = 16 * f + c15;
#pragma unroll
        for (int j = 0; j < 8; ++j) { int k = kq + j; vals[j] = (k < 8) ? Wm1[k * 64 + c] : 0.f; }
    } else if (f < 12) {
        int idx = f - 4, nt = idx >> 1, ks = idx & 1;
        int c = 16 * nt + c15;
#pragma unroll
        for (int j = 0; j < 8; ++j) { int k = 32 * ks + kq + j; vals[j] = Wm2[k * 64 + c]; }
    } else {
        int idx = f - 12, nt = idx >> 1, ks = idx & 1;
        int c = 16 * nt + c15;
        int u = c & 31, m = c >> 5;
        const float* W = (m == 0) ? Wp00 : (m == 1) ? Wp01 : (m == 2) ? Wp10 : Wp11;
        float sc = (m == 3) ? 0.125f * INV_SQRT3 : 0.125f;
#pragma unroll
        for (int j = 0; j < 8; ++j) { int k = 32 * ks + kq + j; vals[j] = W[k * 32 + u] * sc; }
    }
    uint32* o = wf + f * 256 + lane * 4;
#pragma unroll
    for (int w = 0; w < 4; ++w) o[w] = packh2(vals[2 * w], vals[2 * w + 1]);
}

__global__ void node_transform(const float* __restrict__ x,
                               const float* __restrict__ W1_0e,
                               const float* __restrict__ W1_1o,
                               float* __restrict__ ws) {
    int gid = blockIdx.x * blockDim.x + threadIdx.x;
    int n = gid >> 6, w = gid & 63;
    if (n >= N_NODES) return;
    const float* xr = x + n * 128;
    float f0 = 0.f, f1x = 0.f, f1y = 0.f, f1z = 0.f;
#pragma unroll
    for (int u = 0; u < 32; ++u) {
        float w0 = W1_0e[u * 64 + w];
        float w1 = W1_1o[u * 64 + w];
        f0  += xr[u] * w0;
        f1x += xr[32 + u * 3 + 0] * w1;
        f1y += xr[32 + u * 3 + 1] * w1;
        f1z += xr[32 + u * 3 + 2] * w1;
    }
    f0 *= SC_W1; f1x *= SC_W1; f1y *= SC_W1; f1z *= SC_W1;
    if (w < 32) {
        ws[WS_FEAT0 + n * 32 + w] = f0;
        ws[WS_FEAT1 + n * 96 + w * 3 + 0] = f1x;
        ws[WS_FEAT1 + n * 96 + w * 3 + 1] = f1y;
        ws[WS_FEAT1 + n * 96 + w * 3 + 2] = f1z;
    } else {
        int ww = w - 32;
        ws[WS_SELF0 + n * 32 + ww] = f0;
        ws[WS_SELF1 + n * 96 + ww * 3 + 0] = f1x;
        ws[WS_SELF1 + n * 96 + ww * 3 + 1] = f1y;
        ws[WS_SELF1 + n * 96 + ww * 3 + 2] = f1z;
    }
}

// ---- CSR build ----
__global__ void csr_count(const int* __restrict__ dst, int* __restrict__ cnt) {
    int e = blockIdx.x * blockDim.x + threadIdx.x;
    if (e < N_EDGES) atomicAdd(&cnt[dst[e]], 1);
}

__global__ __launch_bounds__(256) void csr_scan(const int* __restrict__ cnt,
                                                int* __restrict__ off,
                                                int* __restrict__ cur) {
    __shared__ int partial[256];
    int t = threadIdx.x;
    const int CHUNK = 40;
    int base = t * CHUNK;
    int s = 0;
#pragma unroll
    for (int j = 0; j < CHUNK; ++j) {
        int idx = base + j;
        s += (idx < N_NODES) ? cnt[idx] : 0;
    }
    partial[t] = s;
    __syncthreads();
    for (int o = 1; o < 256; o <<= 1) {
        int v = partial[t];
        int add = (t >= o) ? partial[t - o] : 0;
        __syncthreads();
        partial[t] = v + add;
        __syncthreads();
    }
    int run = (t > 0) ? partial[t - 1] : 0;
    for (int j = 0; j < CHUNK; ++j) {
        int idx = base + j;
        if (idx < N_NODES) {
            off[idx] = run;
            cur[idx] = run;
            run += cnt[idx];
        }
    }
    if (t == 255) off[N_NODES] = run;
}

__global__ void csr_scatter(const int* __restrict__ dst, int* __restrict__ cur,
                            int* __restrict__ ord) {
    int e = blockIdx.x * blockDim.x + threadIdx.x;
    if (e < N_EDGES) {
        int pos = atomicAdd(&cur[dst[e]], 1);
        ord[pos] = e;
    }
}

// ---- Phase A: MFMA edge MLP ----
// Per wave, per group of 16 edges:
//   h1 = gelu(SC_MLP1 * es@Wm1)        4 MFMA (K=8 zero-padded to 32)
//   h2 = gelu(0.125 * h1@Wm2)          8 MFMA
//   w  = h2@Wp'                        16 MFMA  (scales folded into Wp')
// LDS roundtrips re-layout MFMA D (col-spread) -> A fragments (row-spread).
#define MLP_BLOCKS 512
__global__ __launch_bounds__(256) void edge_mlp(const float* __restrict__ edge_scalar,
                                                const uint32* __restrict__ wf,
                                                uint32* __restrict__ wbuf) {
    __shared__ unsigned short sh[4][1024];   // per-wave 16x64 f16 tile, XOR-swizzled
    int lane = threadIdx.x & 63;
    int wv = threadIdx.x >> 6;
    int wave_id = blockIdx.x * 4 + wv;

    int kq = (lane >> 4) * 8;
    int r15 = lane & 15;

    // preload weight fragments (28 x dwordx4, L2-resident, once per wave)
    const uint32x4* wfp = (const uint32x4*)wf;
    halfx8 wb1[4], wb2[4][2], wbp[8][2];
#pragma unroll
    for (int nt = 0; nt < 4; ++nt)
        wb1[nt] = __builtin_bit_cast(halfx8, wfp[nt * 64 + lane]);
#pragma unroll
    for (int nt = 0; nt < 4; ++nt)
#pragma unroll
        for (int ks = 0; ks < 2; ++ks)
            wb2[nt][ks] = __builtin_bit_cast(halfx8, wfp[(4 + nt * 2 + ks) * 64 + lane]);
#pragma unroll
    for (int nt = 0; nt < 8; ++nt)
#pragma unroll
        for (int ks = 0; ks < 2; ++ks)
            wbp[nt][ks] = __builtin_bit_cast(halfx8, wfp[(12 + nt * 2 + ks) * 64 + lane]);

    const f32x4 z4 = {0.f, 0.f, 0.f, 0.f};
    unsigned short* shw = sh[wv];

    for (int g = wave_id; g < N_EDGES / 16; g += MLP_BLOCKS * 4) {
        int e0 = g * 16;

        // A0: es (K=8, zero-padded) ; lane<16: row=lane, k=0..7
        halfx8 a0 = (halfx8)0;
        if (lane < 16) {
            const float* esp = edge_scalar + (size_t)(e0 + lane) * 8;
            float4 p = *(const float4*)esp;
            float4 q = *(const float4*)(esp + 4);
            a0[0] = (_Float16)p.x; a0[1] = (_Float16)p.y;
            a0[2] = (_Float16)p.z; a0[3] = (_Float16)p.w;
            a0[4] = (_Float16)q.x; a0[5] = (_Float16)q.y;
            a0[6] = (_Float16)q.z; a0[7] = (_Float16)q.w;
        }

        // h1 GEMM
        f32x4 acc1[4];
#pragma unroll
        for (int nt = 0; nt < 4; ++nt)
            acc1[nt] = __builtin_amdgcn_mfma_f32_16x16x32_f16(a0, wb1[nt], z4, 0, 0, 0);
        // gelu -> LDS (D: row=(l>>4)*4+i, col=16nt+r15)
#pragma unroll
        for (int nt = 0; nt < 4; ++nt)
#pragma unroll
            for (int i = 0; i < 4; ++i) {
                float gv = gelu_fast(acc1[nt][i] * SC_MLP1);
                int rr = (lane >> 4) * 4 + i;
                int ix = rr * 64 + 16 * nt + r15;
                shw[ix ^ ((rr & 7) << 3)] = h16(gv);
            }
        // A1 frags: row=r15, k=32ks+kq..+8
        halfx8 a1[2];
#pragma unroll
        for (int ks = 0; ks < 2; ++ks) {
            int ix = r15 * 64 + 32 * ks + kq;
            a1[ks] = __builtin_bit_cast(halfx8,
                       *(const uint32x4*)&shw[ix ^ ((r15 & 7) << 3)]);
        }

        // h2 GEMM
        f32x4 acc2[4];
#pragma unroll
        for (int nt = 0; nt < 4; ++nt) {
            acc2[nt] = __builtin_amdgcn_mfma_f32_16x16x32_f16(a1[0], wb2[nt][0], z4, 0, 0, 0);
            acc2[nt] = __builtin_amdgcn_mfma_f32_16x16x32_f16(a1[1], wb2[nt][1], acc2[nt], 0, 0, 0);
        }
#pragma unroll
        for (int nt = 0; nt < 4; ++nt)
#pragma unroll
            for (int i = 0; i < 4; ++i) {
                float gv = gelu_fast(acc2[nt][i] * SC_MLP2);
                int rr = (lane >> 4) * 4 + i;
                int ix = rr * 64 + 16 * nt + r15;
                shw[ix ^ ((rr & 7) << 3)] = h16(gv);
            }
        halfx8 a2[2];
#pragma unroll
        for (int ks = 0; ks < 2; ++ks) {
            int ix = r15 * 64 + 32 * ks + kq;
            a2[ks] = __builtin_bit_cast(halfx8,
                       *(const uint32x4*)&shw[ix ^ ((r15 & 7) << 3)]);
        }

        // w-projection GEMM, N=128, col = u + 32m
        f32x4 accp[8];
#pragma unroll
        for (int nt = 0; nt < 8; ++nt) {
            accp[nt] = __builtin_amdgcn_mfma_f32_16x16x32_f16(a2[0], wbp[nt][0], z4, 0, 0, 0);
            accp[nt] = __builtin_amdgcn_mfma_f32_16x16x32_f16(a2[1], wbp[nt][1], accp[nt], 0, 0, 0);
        }
        // pack to wbuf[e][64]: [u]=pack(w00,w01), [32+u]=pack(w10,w11)
#pragma unroll
        for (int i = 0; i < 4; ++i) {
            int rr = (lane >> 4) * 4 + i;
            size_t base = ((size_t)(e0 + rr)) * 64 + r15;
            wbuf[base]      = pack_bf2(accp[0][i], accp[2][i]);
            wbuf[base + 16] = pack_bf2(accp[1][i], accp[3][i]);
            wbuf[base + 32] = pack_bf2(accp[4][i], accp[6][i]);
            wbuf[base + 48] = pack_bf2(accp[5][i], accp[7][i]);
        }
    }
}

// ---- Phase B: wave-per-node gather + reduce + W2 + mix ----
__global__ __launch_bounds__(256) void gather(const int* __restrict__ off,
                                              const int* __restrict__ ord,
                                              const int* __restrict__ esrc,
                                              const float* __restrict__ edge_attr,
                                              const uint32* __restrict__ wbuf,
                                              const float* __restrict__ ws_ro,
                                              const float* __restrict__ W2_0e,
                                              const float* __restrict__ W2_1o,
                                              float* __restrict__ out) {
    int wv = __builtin_amdgcn_readfirstlane((int)(threadIdx.x >> 6));
    int lane = threadIdx.x & 63;
    int node = blockIdx.x * 4 + wv;
    int u = lane & 31;
    int half = lane >> 5;

    const float* feat0 = ws_ro + WS_FEAT0;
    const float* feat1 = ws_ro + WS_FEAT1;

    int beg = off[node];
    int end = off[node + 1];

    float a0 = 0.f, a1x = 0.f, a1y = 0.f, a1z = 0.f;

#pragma unroll 2
    for (int i = beg; i < end; ++i) {
        int e = ord[i];
        int src = esrc[e];
        float4 ea = *(const float4*)(edge_attr + (size_t)e * 4);
        uint32 wvv = wbuf[(size_t)e * 64 + (half << 5) + u];
        float wa = __uint_as_float(wvv << 16);
        float wb = __uint_as_float(wvv & 0xffff0000u);
        if (half == 0) {
            float e0 = feat0[src * 32 + u];
            a0  += wa * e0 * ea.x;
            float t = wb * e0;
            a1x += t * ea.y;
            a1y += t * ea.z;
            a1z += t * ea.w;
        } else {
            const float* f1 = feat1 + src * 96 + u * 3;
            float ex = f1[0], ey = f1[1], ez = f1[2];
            float d = ex * ea.y + ey * ea.z + ez * ea.w;
            a0  += wb * d;
            float t = wa * ea.x;
            a1x += t * ex;
            a1y += t * ey;
            a1z += t * ez;
        }
    }

    __shared__ float red[4][256];
    float* r = red[wv];
    int c = (half << 5) + u;
    r[c] = a0;
    int b = 64 + c * 3;
    r[b] = a1x; r[b + 1] = a1y; r[b + 2] = a1z;
    __syncthreads();

    if (half == 0) {
        float acc = 0.f;
#pragma unroll 8
        for (int w = 0; w < 64; ++w) acc += r[w] * W2_0e[w * 32 + u];
        out[node * 128 + u] = COS_MIX * ws_ro[WS_SELF0 + node * 32 + u] + SIN_CONV * acc;
    } else {
        float c0 = 0.f, c1 = 0.f, c2 = 0.f;
#pragma unroll 8
        for (int w = 0; w < 64; ++w) {
            float bw = W2_1o[w * 32 + u];
            c0 += r[64 + w * 3 + 0] * bw;
            c1 += r[64 + w * 3 + 1] * bw;
            c2 += r[64 + w * 3 + 2] * bw;
        }
        int o = node * 128 + 32 + u * 3;
        const float* s1 = ws_ro + WS_SELF1 + node * 96 + u * 3;
        out[o + 0] = COS_MIX * s1[0] + SIN_CONV * c0;
        out[o + 1] = COS_MIX * s1[1] + SIN_CONV * c1;
        out[o + 2] = COS_MIX * s1[2] + SIN_CONV * c2;
    }
}

extern "C" void kernel_launch(void* const* d_in, const int* in_sizes, int n_in,
                              void* d_out, int out_size, void* d_ws, size_t ws_size,
                              hipStream_t stream) {
    const float* node_input  = (const float*)d_in[0];
    const float* edge_attr   = (const float*)d_in[1];
    const float* edge_scalar = (const float*)d_in[2];
    const float* W1_0e       = (const float*)d_in[3];
    const float* W1_1o       = (const float*)d_in[4];
    const float* W_mlp1      = (const float*)d_in[5];
    const float* W_mlp2      = (const float*)d_in[6];
    const float* Wp00        = (const float*)d_in[7];
    const float* Wp01        = (const float*)d_in[8];
    const float* Wp10        = (const float*)d_in[9];
    const float* Wp11        = (const float*)d_in[10];
    const float* W2_0e       = (const float*)d_in[11];
    const float* W2_1o       = (const float*)d_in[12];
    const int*   edge_src    = (const int*)d_in[13];
    const int*   edge_dst    = (const int*)d_in[14];
    float* ws   = (float*)d_ws;
    int*   wsI  = (int*)d_ws;
    uint32* wsU = (uint32*)d_ws;
    float* outp = (float*)d_out;

    hipMemsetAsync(wsI + I_CNT, 0, (N_NODES + 1) * sizeof(int), stream);

    prep_frags<<<7, 256, 0, stream>>>(W_mlp1, W_mlp2, Wp00, Wp01, Wp10, Wp11, wsU + U_WF);
    node_transform<<<(N_NODES * 64 + 255) / 256, 256, 0, stream>>>(node_input, W1_0e, W1_1o, ws);
    csr_count<<<(N_EDGES + 255) / 256, 256, 0, stream>>>(edge_dst, wsI + I_CNT);
    csr_scan<<<1, 256, 0, stream>>>(wsI + I_CNT, wsI + I_OFF, wsI + I_CUR);
    csr_scatter<<<(N_EDGES + 255) / 256, 256, 0, stream>>>(edge_dst, wsI + I_CUR, wsI + I_ORD);
    edge_mlp<<<MLP_BLOCKS, 256, 0, stream>>>(edge_scalar, wsU + U_WF, wsU + U_WBUF);
    gather<<<N_NODES / 4, 256, 0, stream>>>(wsI + I_OFF, wsI + I_ORD, edge_src, edge_attr,
                                            wsU + U_WBUF, ws, W2_0e, W2_1o, outp);
}

// Round 4
// 202.649 us; speedup vs baseline: 21.1676x; 1.5637x over previous
//
#include <hip/hip_runtime.h>

typedef unsigned int uint32;
typedef __attribute__((ext_vector_type(4))) float f32x4;
typedef __attribute__((ext_vector_type(8))) _Float16 halfx8;
typedef __attribute__((ext_vector_type(4))) uint32 uint32x4;

#define N_NODES 10000
#define N_EDGES 320000

// scales
#define SC_W1      0.17677669529663687f   // 1/sqrt(32)
#define SC_MLP1    0.35355339059327373f   // 1/sqrt(8)
#define SC_MLP2    0.125f                 // 1/sqrt(64)
#define INV_SQRT3  0.5773502691896258f
#define COS_MIX    0.9238795325112867f    // cos(pi/8)
#define SIN_CONV   0.04783542904563623f   // sin(pi/8) / sqrt(64)

// ws layout: float indices
#define WS_FEAT0 0        // [N][32]
#define WS_FEAT1 320000   // [N][96]
#define WS_SELF0 1280000  // [N][32]
#define WS_SELF1 1600000  // [N][96]
// int indices (on (int*)ws)
#define I_CNT    2560000  // [N+1]
#define I_OFF    2570016  // [N+1]
#define I_CUR    2580032  // [N]
#define I_ORD    2590048  // [E]
// uint indices (on (uint*)ws)
#define U_WF     2910048  // 28 frags x 64 lanes x 4 uints (f16 pairs)
#define U_WBUF   2917248  // [E][64] packed bf16 pairs

__device__ __forceinline__ uint32 f2bf(float x) {
    uint32 u = __float_as_uint(x);
    return (u + 0x7fffu + ((u >> 16) & 1u)) >> 16;
}
__device__ __forceinline__ uint32 pack_bf2(float a, float b) {
    return f2bf(a) | (f2bf(b) << 16);
}
__device__ __forceinline__ uint32 packh2(float a, float b) {
    _Float16 ha = (_Float16)a, hb = (_Float16)b;
    return (uint32)__builtin_bit_cast(unsigned short, ha) |
           ((uint32)__builtin_bit_cast(unsigned short, hb) << 16);
}
__device__ __forceinline__ unsigned short h16(float x) {
    _Float16 h = (_Float16)x;
    return __builtin_bit_cast(unsigned short, h);
}
// gelu(x) = x * sigmoid(1.5957x + 0.0713x^3)  (== tanh-approx gelu, branch-free)
__device__ __forceinline__ float gelu_fast(float x) {
    float x2 = x * x;
    float z = x * __builtin_fmaf(0.03567740814f, x2, 0.7978845608f);
    float E = __builtin_amdgcn_exp2f(z * -2.885390082f);   // exp(-2z)
    return x * __builtin_amdgcn_rcpf(1.0f + E);
}

// ================= K1: node_transform (coalesced) | csr_count | prep_frags ====
#define K1_NODE_BLOCKS 2500
#define K1_CNT_BLOCKS  1250
#define K1_PREP_BLOCKS 7
__global__ __launch_bounds__(256) void k1_fused(
        const float* __restrict__ x,
        const float* __restrict__ W1_0e, const float* __restrict__ W1_1o,
        const int* __restrict__ edge_dst, int* __restrict__ cnt,
        const float* __restrict__ Wm1, const float* __restrict__ Wm2,
        const float* __restrict__ Wp00, const float* __restrict__ Wp01,
        const float* __restrict__ Wp10, const float* __restrict__ Wp11,
        uint32* __restrict__ wf,
        float* __restrict__ ws) {
    int b = blockIdx.x;
    if (b < K1_NODE_BLOCKS) {
        // ---- node_transform: wave per node, coalesced x-row via LDS ----
        __shared__ float xrow[4][128];
        int wv = threadIdx.x >> 6, lane = threadIdx.x & 63;
        int node = b * 4 + wv;
        float2 v = *(const float2*)(x + (size_t)node * 128 + lane * 2);
        xrow[wv][lane * 2]     = v.x;
        xrow[wv][lane * 2 + 1] = v.y;
        __syncthreads();
        const float* sx = xrow[wv];
        int w = lane;
        float f0 = 0.f, f1x = 0.f, f1y = 0.f, f1z = 0.f;
#pragma unroll
        for (int u = 0; u < 32; ++u) {
            float w0 = W1_0e[u * 64 + w];
            float w1 = W1_1o[u * 64 + w];
            f0  += sx[u] * w0;
            f1x += sx[32 + u * 3 + 0] * w1;
            f1y += sx[32 + u * 3 + 1] * w1;
            f1z += sx[32 + u * 3 + 2] * w1;
        }
        f0 *= SC_W1; f1x *= SC_W1; f1y *= SC_W1; f1z *= SC_W1;
        if (w < 32) {
            ws[WS_FEAT0 + node * 32 + w] = f0;
            ws[WS_FEAT1 + node * 96 + w * 3 + 0] = f1x;
            ws[WS_FEAT1 + node * 96 + w * 3 + 1] = f1y;
            ws[WS_FEAT1 + node * 96 + w * 3 + 2] = f1z;
        } else {
            int ww = w - 32;
            ws[WS_SELF0 + node * 32 + ww] = f0;
            ws[WS_SELF1 + node * 96 + ww * 3 + 0] = f1x;
            ws[WS_SELF1 + node * 96 + ww * 3 + 1] = f1y;
            ws[WS_SELF1 + node * 96 + ww * 3 + 2] = f1z;
        }
    } else if (b < K1_NODE_BLOCKS + K1_CNT_BLOCKS) {
        // ---- csr_count ----
        int e = (b - K1_NODE_BLOCKS) * 256 + threadIdx.x;   // 1250*256 == N_EDGES
        atomicAdd(&cnt[edge_dst[e]], 1);
    } else {
        // ---- prep_frags ----
        int gid = (b - K1_NODE_BLOCKS - K1_CNT_BLOCKS) * 256 + threadIdx.x; // 7*256 == 28*64
        int f = gid >> 6, lane = gid & 63;
        int kq = (lane >> 4) * 8;
        int c15 = lane & 15;
        float vals[8];
        if (f < 4) {
            int c = 16 * f + c15;
#pragma unroll
            for (int j = 0; j < 8; ++j) { int k = kq + j; vals[j] = (k < 8) ? Wm1[k * 64 + c] : 0.f; }
        } else if (f < 12) {
            int idx = f - 4, nt = idx >> 1, ks = idx & 1;
            int c = 16 * nt + c15;
#pragma unroll
            for (int j = 0; j < 8; ++j) { int k = 32 * ks + kq + j; vals[j] = Wm2[k * 64 + c]; }
        } else {
            int idx = f - 12, nt = idx >> 1, ks = idx & 1;
            int c = 16 * nt + c15;
            int u = c & 31, m = c >> 5;
            const float* W = (m == 0) ? Wp00 : (m == 1) ? Wp01 : (m == 2) ? Wp10 : Wp11;
            float sc = (m == 3) ? 0.125f * INV_SQRT3 : 0.125f;
#pragma unroll
            for (int j = 0; j < 8; ++j) { int k = 32 * ks + kq + j; vals[j] = W[k * 32 + u] * sc; }
        }
        uint32* o = wf + f * 256 + lane * 4;
#pragma unroll
        for (int w = 0; w < 4; ++w) o[w] = packh2(vals[2 * w], vals[2 * w + 1]);
    }
}

// ================= K2: csr_scan (single block) =================
__global__ __launch_bounds__(256) void csr_scan(const int* __restrict__ cnt,
                                                int* __restrict__ off,
                                                int* __restrict__ cur) {
    __shared__ int partial[256];
    int t = threadIdx.x;
    const int CHUNK = 40;
    int base = t * CHUNK;
    int s = 0;
#pragma unroll
    for (int j = 0; j < CHUNK; ++j) {
        int idx = base + j;
        s += (idx < N_NODES) ? cnt[idx] : 0;
    }
    partial[t] = s;
    __syncthreads();
    for (int o = 1; o < 256; o <<= 1) {
        int v = partial[t];
        int add = (t >= o) ? partial[t - o] : 0;
        __syncthreads();
        partial[t] = v + add;
        __syncthreads();
    }
    int run = (t > 0) ? partial[t - 1] : 0;
    for (int j = 0; j < CHUNK; ++j) {
        int idx = base + j;
        if (idx < N_NODES) {
            off[idx] = run;
            cur[idx] = run;
            run += cnt[idx];
        }
    }
    if (t == 255) off[N_NODES] = run;
}

// ================= K3: edge_mlp (MFMA) | csr_scatter =================
#define MLP_BLOCKS 512
#define K3_SCAT_BLOCKS 1250
__global__ __launch_bounds__(256) void k3_fused(
        const float* __restrict__ edge_scalar, const uint32* __restrict__ wf,
        uint32* __restrict__ wbuf,
        const int* __restrict__ dst, int* __restrict__ cur, int* __restrict__ ord) {
    __shared__ unsigned short sh[4][1024];
    int b = blockIdx.x;
    if (b >= MLP_BLOCKS) {
        int e = (b - MLP_BLOCKS) * 256 + threadIdx.x;   // 1250*256 == N_EDGES
        int pos = atomicAdd(&cur[dst[e]], 1);
        ord[pos] = e;
        return;
    }
    // ---- edge_mlp ----
    int lane = threadIdx.x & 63;
    int wv = threadIdx.x >> 6;
    int wave_id = b * 4 + wv;

    int kq = (lane >> 4) * 8;
    int r15 = lane & 15;

    const uint32x4* wfp = (const uint32x4*)wf;
    halfx8 wb1[4], wb2[4][2], wbp[8][2];
#pragma unroll
    for (int nt = 0; nt < 4; ++nt)
        wb1[nt] = __builtin_bit_cast(halfx8, wfp[nt * 64 + lane]);
#pragma unroll
    for (int nt = 0; nt < 4; ++nt)
#pragma unroll
        for (int ks = 0; ks < 2; ++ks)
            wb2[nt][ks] = __builtin_bit_cast(halfx8, wfp[(4 + nt * 2 + ks) * 64 + lane]);
#pragma unroll
    for (int nt = 0; nt < 8; ++nt)
#pragma unroll
        for (int ks = 0; ks < 2; ++ks)
            wbp[nt][ks] = __builtin_bit_cast(halfx8, wfp[(12 + nt * 2 + ks) * 64 + lane]);

    const f32x4 z4 = {0.f, 0.f, 0.f, 0.f};
    unsigned short* shw = sh[wv];

    for (int g = wave_id; g < N_EDGES / 16; g += MLP_BLOCKS * 4) {
        int e0 = g * 16;

        halfx8 a0 = (halfx8)0;
        if (lane < 16) {
            const float* esp = edge_scalar + (size_t)(e0 + lane) * 8;
            float4 p = *(const float4*)esp;
            float4 q = *(const float4*)(esp + 4);
            a0[0] = (_Float16)p.x; a0[1] = (_Float16)p.y;
            a0[2] = (_Float16)p.z; a0[3] = (_Float16)p.w;
            a0[4] = (_Float16)q.x; a0[5] = (_Float16)q.y;
            a0[6] = (_Float16)q.z; a0[7] = (_Float16)q.w;
        }

        f32x4 acc1[4];
#pragma unroll
        for (int nt = 0; nt < 4; ++nt)
            acc1[nt] = __builtin_amdgcn_mfma_f32_16x16x32_f16(a0, wb1[nt], z4, 0, 0, 0);
#pragma unroll
        for (int nt = 0; nt < 4; ++nt)
#pragma unroll
            for (int i = 0; i < 4; ++i) {
                float gv = gelu_fast(acc1[nt][i] * SC_MLP1);
                int rr = (lane >> 4) * 4 + i;
                int ix = rr * 64 + 16 * nt + r15;
                shw[ix ^ ((rr & 7) << 3)] = h16(gv);
            }
        halfx8 a1[2];
#pragma unroll
        for (int ks = 0; ks < 2; ++ks) {
            int ix = r15 * 64 + 32 * ks + kq;
            a1[ks] = __builtin_bit_cast(halfx8,
                       *(const uint32x4*)&shw[ix ^ ((r15 & 7) << 3)]);
        }

        f32x4 acc2[4];
#pragma unroll
        for (int nt = 0; nt < 4; ++nt) {
            acc2[nt] = __builtin_amdgcn_mfma_f32_16x16x32_f16(a1[0], wb2[nt][0], z4, 0, 0, 0);
            acc2[nt] = __builtin_amdgcn_mfma_f32_16x16x32_f16(a1[1], wb2[nt][1], acc2[nt], 0, 0, 0);
        }
#pragma unroll
        for (int nt = 0; nt < 4; ++nt)
#pragma unroll
            for (int i = 0; i < 4; ++i) {
                float gv = gelu_fast(acc2[nt][i] * SC_MLP2);
                int rr = (lane >> 4) * 4 + i;
                int ix = rr * 64 + 16 * nt + r15;
                shw[ix ^ ((rr & 7) << 3)] = h16(gv);
            }
        halfx8 a2[2];
#pragma unroll
        for (int ks = 0; ks < 2; ++ks) {
            int ix = r15 * 64 + 32 * ks + kq;
            a2[ks] = __builtin_bit_cast(halfx8,
                       *(const uint32x4*)&shw[ix ^ ((r15 & 7) << 3)]);
        }

        f32x4 accp[8];
#pragma unroll
        for (int nt = 0; nt < 8; ++nt) {
            accp[nt] = __builtin_amdgcn_mfma_f32_16x16x32_f16(a2[0], wbp[nt][0], z4, 0, 0, 0);
            accp[nt] = __builtin_amdgcn_mfma_f32_16x16x32_f16(a2[1], wbp[nt][1], accp[nt], 0, 0, 0);
        }
#pragma unroll
        for (int i = 0; i < 4; ++i) {
            int rr = (lane >> 4) * 4 + i;
            size_t base = ((size_t)(e0 + rr)) * 64 + r15;
            wbuf[base]      = pack_bf2(accp[0][i], accp[2][i]);
            wbuf[base + 16] = pack_bf2(accp[1][i], accp[3][i]);
            wbuf[base + 32] = pack_bf2(accp[4][i], accp[6][i]);
            wbuf[base + 48] = pack_bf2(accp[5][i], accp[7][i]);
        }
    }
}

// ================= K4: gather =================
__global__ __launch_bounds__(256) void gather(const int* __restrict__ off,
                                              const int* __restrict__ ord,
                                              const int* __restrict__ esrc,
                                              const float* __restrict__ edge_attr,
                                              const uint32* __restrict__ wbuf,
                                              const float* __restrict__ ws_ro,
                                              const float* __restrict__ W2_0e,
                                              const float* __restrict__ W2_1o,
                                              float* __restrict__ out) {
    int wv = __builtin_amdgcn_readfirstlane((int)(threadIdx.x >> 6));
    int lane = threadIdx.x & 63;
    int node = blockIdx.x * 4 + wv;
    int u = lane & 31;
    int half = lane >> 5;

    const float* feat0 = ws_ro + WS_FEAT0;
    const float* feat1 = ws_ro + WS_FEAT1;

    int beg = off[node];
    int end = off[node + 1];

    float a0 = 0.f, a1x = 0.f, a1y = 0.f, a1z = 0.f;

#pragma unroll 2
    for (int i = beg; i < end; ++i) {
        int e = __builtin_amdgcn_readfirstlane(ord[i]);      // wave-uniform -> SGPR
        int src = __builtin_amdgcn_readfirstlane(esrc[e]);   // wave-uniform -> SGPR
        float4 ea = *(const float4*)(edge_attr + (size_t)e * 4);
        uint32 wvv = wbuf[(size_t)e * 64 + (half << 5) + u];
        float wa = __uint_as_float(wvv << 16);
        float wb = __uint_as_float(wvv & 0xffff0000u);
        if (half == 0) {
            float e0 = feat0[src * 32 + u];
            a0  += wa * e0 * ea.x;
            float t = wb * e0;
            a1x += t * ea.y;
            a1y += t * ea.z;
            a1z += t * ea.w;
        } else {
            const float* f1 = feat1 + src * 96 + u * 3;
            float ex = f1[0], ey = f1[1], ez = f1[2];
            float d = ex * ea.y + ey * ea.z + ez * ea.w;
            a0  += wb * d;
            float t = wa * ea.x;
            a1x += t * ex;
            a1y += t * ey;
            a1z += t * ez;
        }
    }

    __shared__ float red[4][256];
    float* r = red[wv];
    int c = (half << 5) + u;
    r[c] = a0;
    int b = 64 + c * 3;
    r[b] = a1x; r[b + 1] = a1y; r[b + 2] = a1z;
    __syncthreads();

    if (half == 0) {
        float acc = 0.f;
#pragma unroll 8
        for (int w = 0; w < 64; ++w) acc += r[w] * W2_0e[w * 32 + u];
        out[node * 128 + u] = COS_MIX * ws_ro[WS_SELF0 + node * 32 + u] + SIN_CONV * acc;
    } else {
        float c0 = 0.f, c1 = 0.f, c2 = 0.f;
#pragma unroll 8
        for (int w = 0; w < 64; ++w) {
            float bw = W2_1o[w * 32 + u];
            c0 += r[64 + w * 3 + 0] * bw;
            c1 += r[64 + w * 3 + 1] * bw;
            c2 += r[64 + w * 3 + 2] * bw;
        }
        int o = node * 128 + 32 + u * 3;
        const float* s1 = ws_ro + WS_SELF1 + node * 96 + u * 3;
        out[o + 0] = COS_MIX * s1[0] + SIN_CONV * c0;
        out[o + 1] = COS_MIX * s1[1] + SIN_CONV * c1;
        out[o + 2] = COS_MIX * s1[2] + SIN_CONV * c2;
    }
}

extern "C" void kernel_launch(void* const* d_in, const int* in_sizes, int n_in,
                              void* d_out, int out_size, void* d_ws, size_t ws_size,
                              hipStream_t stream) {
    const float* node_input  = (const float*)d_in[0];
    const float* edge_attr   = (const float*)d_in[1];
    const float* edge_scalar = (const float*)d_in[2];
    const float* W1_0e       = (const float*)d_in[3];
    const float* W1_1o       = (const float*)d_in[4];
    const float* W_mlp1      = (const float*)d_in[5];
    const float* W_mlp2      = (const float*)d_in[6];
    const float* Wp00        = (const float*)d_in[7];
    const float* Wp01        = (const float*)d_in[8];
    const float* Wp10        = (const float*)d_in[9];
    const float* Wp11        = (const float*)d_in[10];
    const float* W2_0e       = (const float*)d_in[11];
    const float* W2_1o       = (const float*)d_in[12];
    const int*   edge_src    = (const int*)d_in[13];
    const int*   edge_dst    = (const int*)d_in[14];
    float* ws   = (float*)d_ws;
    int*   wsI  = (int*)d_ws;
    uint32* wsU = (uint32*)d_ws;
    float* outp = (float*)d_out;

    hipMemsetAsync(wsI + I_CNT, 0, (N_NODES + 1) * sizeof(int), stream);

    k1_fused<<<K1_NODE_BLOCKS + K1_CNT_BLOCKS + K1_PREP_BLOCKS, 256, 0, stream>>>(
        node_input, W1_0e, W1_1o, edge_dst, wsI + I_CNT,
        W_mlp1, W_mlp2, Wp00, Wp01, Wp10, Wp11, wsU + U_WF, ws);
    csr_scan<<<1, 256, 0, stream>>>(wsI + I_CNT, wsI + I_OFF, wsI + I_CUR);
    k3_fused<<<MLP_BLOCKS + K3_SCAT_BLOCKS, 256, 0, stream>>>(
        edge_scalar, wsU + U_WF, wsU + U_WBUF, edge_dst, wsI + I_CUR, wsI + I_ORD);
    gather<<<N_NODES / 4, 256, 0, stream>>>(wsI + I_OFF, wsI + I_ORD, edge_src, edge_attr,
                                            wsU + U_WBUF, ws, W2_0e, W2_1o, outp);
}

// Round 5
// 199.670 us; speedup vs baseline: 21.4835x; 1.0149x over previous
//
#include <hip/hip_runtime.h>

typedef unsigned int uint32;
typedef __attribute__((ext_vector_type(4))) float f32x4;
typedef __attribute__((ext_vector_type(8))) _Float16 halfx8;
typedef __attribute__((ext_vector_type(4))) uint32 uint32x4;

#define N_NODES 10000
#define N_EDGES 320000

// scales
#define SC_W1      0.17677669529663687f   // 1/sqrt(32)
#define SC_MLP1    0.35355339059327373f   // 1/sqrt(8)
#define SC_MLP2    0.125f                 // 1/sqrt(64)
#define INV_SQRT3  0.5773502691896258f
#define COS_MIX    0.9238795325112867f    // cos(pi/8)
#define SIN_CONV   0.04783542904563623f   // sin(pi/8) / sqrt(64)

// ws layout: float indices
#define WS_FEAT0 0        // [N][32]
#define WS_FEAT1 320000   // [N][96]
#define WS_SELF0 1280000  // [N][32]
#define WS_SELF1 1600000  // [N][96]
// int indices (on (int*)ws)
#define I_CNT    2560000  // [N+1]
#define I_OFF    2570016  // [N+1]
#define I_CUR    2580032  // [N]
#define I_ORD    2590048  // [E]
// uint indices (on (uint*)ws)
#define U_WF     2910048  // 28 frags x 64 lanes x 4 uints (f16 pairs)
#define U_WBUF   2917248  // [E][64] packed bf16 pairs

__device__ __forceinline__ uint32 f2bf(float x) {
    uint32 u = __float_as_uint(x);
    return (u + 0x7fffu + ((u >> 16) & 1u)) >> 16;
}
__device__ __forceinline__ uint32 pack_bf2(float a, float b) {
    return f2bf(a) | (f2bf(b) << 16);
}
__device__ __forceinline__ uint32 packh2(float a, float b) {
    _Float16 ha = (_Float16)a, hb = (_Float16)b;
    return (uint32)__builtin_bit_cast(unsigned short, ha) |
           ((uint32)__builtin_bit_cast(unsigned short, hb) << 16);
}
__device__ __forceinline__ unsigned short h16(float x) {
    _Float16 h = (_Float16)x;
    return __builtin_bit_cast(unsigned short, h);
}
// gelu(x) = x * sigmoid(1.5957x + 0.0713x^3)  (== tanh-approx gelu, branch-free)
__device__ __forceinline__ float gelu_fast(float x) {
    float x2 = x * x;
    float z = x * __builtin_fmaf(0.03567740814f, x2, 0.7978845608f);
    float E = __builtin_amdgcn_exp2f(z * -2.885390082f);   // exp(-2z)
    return x * __builtin_amdgcn_rcpf(1.0f + E);
}

// ================= K1: node_transform (coalesced) | csr_count | prep_frags ====
#define K1_NODE_BLOCKS 2500
#define K1_CNT_BLOCKS  1250
#define K1_PREP_BLOCKS 7
__global__ __launch_bounds__(256) void k1_fused(
        const float* __restrict__ x,
        const float* __restrict__ W1_0e, const float* __restrict__ W1_1o,
        const int* __restrict__ edge_dst, int* __restrict__ cnt,
        const float* __restrict__ Wm1, const float* __restrict__ Wm2,
        const float* __restrict__ Wp00, const float* __restrict__ Wp01,
        const float* __restrict__ Wp10, const float* __restrict__ Wp11,
        uint32* __restrict__ wf,
        float* __restrict__ ws) {
    int b = blockIdx.x;
    if (b < K1_NODE_BLOCKS) {
        // ---- node_transform: wave per node, coalesced x-row via LDS ----
        __shared__ float xrow[4][128];
        int wv = threadIdx.x >> 6, lane = threadIdx.x & 63;
        int node = b * 4 + wv;
        float2 v = *(const float2*)(x + (size_t)node * 128 + lane * 2);
        xrow[wv][lane * 2]     = v.x;
        xrow[wv][lane * 2 + 1] = v.y;
        __syncthreads();
        const float* sx = xrow[wv];
        int w = lane;
        float f0 = 0.f, f1x = 0.f, f1y = 0.f, f1z = 0.f;
#pragma unroll
        for (int u = 0; u < 32; ++u) {
            float w0 = W1_0e[u * 64 + w];
            float w1 = W1_1o[u * 64 + w];
            f0  += sx[u] * w0;
            f1x += sx[32 + u * 3 + 0] * w1;
            f1y += sx[32 + u * 3 + 1] * w1;
            f1z += sx[32 + u * 3 + 2] * w1;
        }
        f0 *= SC_W1; f1x *= SC_W1; f1y *= SC_W1; f1z *= SC_W1;
        if (w < 32) {
            ws[WS_FEAT0 + node * 32 + w] = f0;
            ws[WS_FEAT1 + node * 96 + w * 3 + 0] = f1x;
            ws[WS_FEAT1 + node * 96 + w * 3 + 1] = f1y;
            ws[WS_FEAT1 + node * 96 + w * 3 + 2] = f1z;
        } else {
            int ww = w - 32;
            ws[WS_SELF0 + node * 32 + ww] = f0;
            ws[WS_SELF1 + node * 96 + ww * 3 + 0] = f1x;
            ws[WS_SELF1 + node * 96 + ww * 3 + 1] = f1y;
            ws[WS_SELF1 + node * 96 + ww * 3 + 2] = f1z;
        }
    } else if (b < K1_NODE_BLOCKS + K1_CNT_BLOCKS) {
        // ---- csr_count ----
        int e = (b - K1_NODE_BLOCKS) * 256 + threadIdx.x;   // 1250*256 == N_EDGES
        atomicAdd(&cnt[edge_dst[e]], 1);
    } else {
        // ---- prep_frags ----
        int gid = (b - K1_NODE_BLOCKS - K1_CNT_BLOCKS) * 256 + threadIdx.x; // 7*256 == 28*64
        int f = gid >> 6, lane = gid & 63;
        int kq = (lane >> 4) * 8;
        int c15 = lane & 15;
        float vals[8];
        if (f < 4) {
            int c = 16 * f + c15;
#pragma unroll
            for (int j = 0; j < 8; ++j) { int k = kq + j; vals[j] = (k < 8) ? Wm1[k * 64 + c] : 0.f; }
        } else if (f < 12) {
            int idx = f - 4, nt = idx >> 1, ks = idx & 1;
            int c = 16 * nt + c15;
#pragma unroll
            for (int j = 0; j < 8; ++j) { int k = 32 * ks + kq + j; vals[j] = Wm2[k * 64 + c]; }
        } else {
            int idx = f - 12, nt = idx >> 1, ks = idx & 1;
            int c = 16 * nt + c15;
            int u = c & 31, m = c >> 5;
            const float* W = (m == 0) ? Wp00 : (m == 1) ? Wp01 : (m == 2) ? Wp10 : Wp11;
            float sc = (m == 3) ? 0.125f * INV_SQRT3 : 0.125f;
#pragma unroll
            for (int j = 0; j < 8; ++j) { int k = 32 * ks + kq + j; vals[j] = W[k * 32 + u] * sc; }
        }
        uint32* o = wf + f * 256 + lane * 4;
#pragma unroll
        for (int w = 0; w < 4; ++w) o[w] = packh2(vals[2 * w], vals[2 * w + 1]);
    }
}

// ================= K2: csr_scan (single block) =================
__global__ __launch_bounds__(256) void csr_scan(const int* __restrict__ cnt,
                                                int* __restrict__ off,
                                                int* __restrict__ cur) {
    __shared__ int partial[256];
    int t = threadIdx.x;
    const int CHUNK = 40;
    int base = t * CHUNK;
    int s = 0;
#pragma unroll
    for (int j = 0; j < CHUNK; ++j) {
        int idx = base + j;
        s += (idx < N_NODES) ? cnt[idx] : 0;
    }
    partial[t] = s;
    __syncthreads();
    for (int o = 1; o < 256; o <<= 1) {
        int v = partial[t];
        int add = (t >= o) ? partial[t - o] : 0;
        __syncthreads();
        partial[t] = v + add;
        __syncthreads();
    }
    int run = (t > 0) ? partial[t - 1] : 0;
    for (int j = 0; j < CHUNK; ++j) {
        int idx = base + j;
        if (idx < N_NODES) {
            off[idx] = run;
            cur[idx] = run;
            run += cnt[idx];
        }
    }
    if (t == 255) off[N_NODES] = run;
}

// ================= K3: edge_mlp (MFMA) | csr_scatter =================
#define MLP_BLOCKS 1250
#define K3_SCAT_BLOCKS 1250
__global__ __launch_bounds__(256) void k3_fused(
        const float* __restrict__ edge_scalar, const uint32* __restrict__ wf,
        uint32* __restrict__ wbuf,
        const int* __restrict__ dst, int* __restrict__ cur, int* __restrict__ ord) {
    __shared__ unsigned short sh[4][1024];
    int b = blockIdx.x;
    if (b >= MLP_BLOCKS) {
        int e = (b - MLP_BLOCKS) * 256 + threadIdx.x;   // 1250*256 == N_EDGES
        int pos = atomicAdd(&cur[dst[e]], 1);
        ord[pos] = e;
        return;
    }
    // ---- edge_mlp ----
    int lane = threadIdx.x & 63;
    int wv = threadIdx.x >> 6;
    int wave_id = b * 4 + wv;

    int kq = (lane >> 4) * 8;
    int r15 = lane & 15;

    const uint32x4* wfp = (const uint32x4*)wf;
    halfx8 wb1[4], wb2[4][2], wbp[8][2];
#pragma unroll
    for (int nt = 0; nt < 4; ++nt)
        wb1[nt] = __builtin_bit_cast(halfx8, wfp[nt * 64 + lane]);
#pragma unroll
    for (int nt = 0; nt < 4; ++nt)
#pragma unroll
        for (int ks = 0; ks < 2; ++ks)
            wb2[nt][ks] = __builtin_bit_cast(halfx8, wfp[(4 + nt * 2 + ks) * 64 + lane]);
#pragma unroll
    for (int nt = 0; nt < 8; ++nt)
#pragma unroll
        for (int ks = 0; ks < 2; ++ks)
            wbp[nt][ks] = __builtin_bit_cast(halfx8, wfp[(12 + nt * 2 + ks) * 64 + lane]);

    const f32x4 z4 = {0.f, 0.f, 0.f, 0.f};
    unsigned short* shw = sh[wv];

    for (int g = wave_id; g < N_EDGES / 16; g += MLP_BLOCKS * 4) {
        int e0 = g * 16;

        halfx8 a0 = (halfx8)0;
        if (lane < 16) {
            const float* esp = edge_scalar + (size_t)(e0 + lane) * 8;
            float4 p = *(const float4*)esp;
            float4 q = *(const float4*)(esp + 4);
            a0[0] = (_Float16)p.x; a0[1] = (_Float16)p.y;
            a0[2] = (_Float16)p.z; a0[3] = (_Float16)p.w;
            a0[4] = (_Float16)q.x; a0[5] = (_Float16)q.y;
            a0[6] = (_Float16)q.z; a0[7] = (_Float16)q.w;
        }

        f32x4 acc1[4];
#pragma unroll
        for (int nt = 0; nt < 4; ++nt)
            acc1[nt] = __builtin_amdgcn_mfma_f32_16x16x32_f16(a0, wb1[nt], z4, 0, 0, 0);
#pragma unroll
        for (int nt = 0; nt < 4; ++nt)
#pragma unroll
            for (int i = 0; i < 4; ++i) {
                float gv = gelu_fast(acc1[nt][i] * SC_MLP1);
                int rr = (lane >> 4) * 4 + i;
                int ix = rr * 64 + 16 * nt + r15;
                shw[ix ^ ((rr & 7) << 3)] = h16(gv);
            }
        halfx8 a1[2];
#pragma unroll
        for (int ks = 0; ks < 2; ++ks) {
            int ix = r15 * 64 + 32 * ks + kq;
            a1[ks] = __builtin_bit_cast(halfx8,
                       *(const uint32x4*)&shw[ix ^ ((r15 & 7) << 3)]);
        }

        f32x4 acc2[4];
#pragma unroll
        for (int nt = 0; nt < 4; ++nt) {
            acc2[nt] = __builtin_amdgcn_mfma_f32_16x16x32_f16(a1[0], wb2[nt][0], z4, 0, 0, 0);
            acc2[nt] = __builtin_amdgcn_mfma_f32_16x16x32_f16(a1[1], wb2[nt][1], acc2[nt], 0, 0, 0);
        }
#pragma unroll
        for (int nt = 0; nt < 4; ++nt)
#pragma unroll
            for (int i = 0; i < 4; ++i) {
                float gv = gelu_fast(acc2[nt][i] * SC_MLP2);
                int rr = (lane >> 4) * 4 + i;
                int ix = rr * 64 + 16 * nt + r15;
                shw[ix ^ ((rr & 7) << 3)] = h16(gv);
            }
        halfx8 a2[2];
#pragma unroll
        for (int ks = 0; ks < 2; ++ks) {
            int ix = r15 * 64 + 32 * ks + kq;
            a2[ks] = __builtin_bit_cast(halfx8,
                       *(const uint32x4*)&shw[ix ^ ((r15 & 7) << 3)]);
        }

        f32x4 accp[8];
#pragma unroll
        for (int nt = 0; nt < 8; ++nt) {
            accp[nt] = __builtin_amdgcn_mfma_f32_16x16x32_f16(a2[0], wbp[nt][0], z4, 0, 0, 0);
            accp[nt] = __builtin_amdgcn_mfma_f32_16x16x32_f16(a2[1], wbp[nt][1], accp[nt], 0, 0, 0);
        }
#pragma unroll
        for (int i = 0; i < 4; ++i) {
            int rr = (lane >> 4) * 4 + i;
            size_t base = ((size_t)(e0 + rr)) * 64 + r15;
            wbuf[base]      = pack_bf2(accp[0][i], accp[2][i]);
            wbuf[base + 16] = pack_bf2(accp[1][i], accp[3][i]);
            wbuf[base + 32] = pack_bf2(accp[4][i], accp[6][i]);
            wbuf[base + 48] = pack_bf2(accp[5][i], accp[7][i]);
        }
    }
}

// ================= K4: gather (batched indices + readlane) =================
__global__ __launch_bounds__(256) void gather(const int* __restrict__ off,
                                              const int* __restrict__ ord,
                                              const int* __restrict__ esrc,
                                              const float* __restrict__ edge_attr,
                                              const uint32* __restrict__ wbuf,
                                              const float* __restrict__ ws_ro,
                                              const float* __restrict__ W2_0e,
                                              const float* __restrict__ W2_1o,
                                              float* __restrict__ out) {
    int wv = threadIdx.x >> 6;
    int lane = threadIdx.x & 63;
    int node = blockIdx.x * 4 + wv;
    int u = lane & 31;
    int half = lane >> 5;

    const float* feat0 = ws_ro + WS_FEAT0;
    const float* feat1 = ws_ro + WS_FEAT1;

    int beg = off[node];
    int end = off[node + 1];

    float a0 = 0.f, a1x = 0.f, a1y = 0.f, a1z = 0.f;

    for (int i0 = beg; i0 < end; i0 += 64) {
        int nn = end - i0;
        if (nn > 64) nn = 64;
        // batch-load up to 64 edge ids + their srcs into registers (one
        // coalesced load + one gather); inner loop gets them via readlane,
        // so no per-iteration address-chain memory dependence remains.
        int idx = i0 + ((lane < nn) ? lane : 0);
        int ev = ord[idx];
        int sv = esrc[ev];
#pragma unroll 4
        for (int j = 0; j < nn; ++j) {
            int e   = __builtin_amdgcn_readlane(ev, j);   // SGPR
            int src = __builtin_amdgcn_readlane(sv, j);   // SGPR
            float4 ea = *(const float4*)(edge_attr + (size_t)e * 4);
            uint32 wvv = wbuf[(size_t)e * 64 + (half << 5) + u];
            float wa = __uint_as_float(wvv << 16);
            float wb = __uint_as_float(wvv & 0xffff0000u);
            if (half == 0) {
                float e0 = feat0[src * 32 + u];
                a0  += wa * e0 * ea.x;
                float t = wb * e0;
                a1x += t * ea.y;
                a1y += t * ea.z;
                a1z += t * ea.w;
            } else {
                const float* f1 = feat1 + src * 96 + u * 3;
                float ex = f1[0], ey = f1[1], ez = f1[2];
                float d = ex * ea.y + ey * ea.z + ez * ea.w;
                a0  += wb * d;
                float t = wa * ea.x;
                a1x += t * ex;
                a1y += t * ey;
                a1z += t * ez;
            }
        }
    }

    __shared__ float red[4][256];
    float* r = red[wv];
    int c = (half << 5) + u;
    r[c] = a0;
    int b = 64 + c * 3;
    r[b] = a1x; r[b + 1] = a1y; r[b + 2] = a1z;
    __syncthreads();

    if (half == 0) {
        float acc = 0.f;
#pragma unroll 8
        for (int w = 0; w < 64; ++w) acc += r[w] * W2_0e[w * 32 + u];
        out[node * 128 + u] = COS_MIX * ws_ro[WS_SELF0 + node * 32 + u] + SIN_CONV * acc;
    } else {
        float c0 = 0.f, c1 = 0.f, c2 = 0.f;
#pragma unroll 8
        for (int w = 0; w < 64; ++w) {
            float bw = W2_1o[w * 32 + u];
            c0 += r[64 + w * 3 + 0] * bw;
            c1 += r[64 + w * 3 + 1] * bw;
            c2 += r[64 + w * 3 + 2] * bw;
        }
        int o = node * 128 + 32 + u * 3;
        const float* s1 = ws_ro + WS_SELF1 + node * 96 + u * 3;
        out[o + 0] = COS_MIX * s1[0] + SIN_CONV * c0;
        out[o + 1] = COS_MIX * s1[1] + SIN_CONV * c1;
        out[o + 2] = COS_MIX * s1[2] + SIN_CONV * c2;
    }
}

extern "C" void kernel_launch(void* const* d_in, const int* in_sizes, int n_in,
                              void* d_out, int out_size, void* d_ws, size_t ws_size,
                              hipStream_t stream) {
    const float* node_input  = (const float*)d_in[0];
    const float* edge_attr   = (const float*)d_in[1];
    const float* edge_scalar = (const float*)d_in[2];
    const float* W1_0e       = (const float*)d_in[3];
    const float* W1_1o       = (const float*)d_in[4];
    const float* W_mlp1      = (const float*)d_in[5];
    const float* W_mlp2      = (const float*)d_in[6];
    const float* Wp00        = (const float*)d_in[7];
    const float* Wp01        = (const float*)d_in[8];
    const float* Wp10        = (const float*)d_in[9];
    const float* Wp11        = (const float*)d_in[10];
    const float* W2_0e       = (const float*)d_in[11];
    const float* W2_1o       = (const float*)d_in[12];
    const int*   edge_src    = (const int*)d_in[13];
    const int*   edge_dst    = (const int*)d_in[14];
    float* ws   = (float*)d_ws;
    int*   wsI  = (int*)d_ws;
    uint32* wsU = (uint32*)d_ws;
    float* outp = (float*)d_out;

    hipMemsetAsync(wsI + I_CNT, 0, (N_NODES + 1) * sizeof(int), stream);

    k1_fused<<<K1_NODE_BLOCKS + K1_CNT_BLOCKS + K1_PREP_BLOCKS, 256, 0, stream>>>(
        node_input, W1_0e, W1_1o, edge_dst, wsI + I_CNT,
        W_mlp1, W_mlp2, Wp00, Wp01, Wp10, Wp11, wsU + U_WF, ws);
    csr_scan<<<1, 256, 0, stream>>>(wsI + I_CNT, wsI + I_OFF, wsI + I_CUR);
    k3_fused<<<MLP_BLOCKS + K3_SCAT_BLOCKS, 256, 0, stream>>>(
        edge_scalar, wsU + U_WF, wsU + U_WBUF, edge_dst, wsI + I_CUR, wsI + I_ORD);
    gather<<<N_NODES / 4, 256, 0, stream>>>(wsI + I_OFF, wsI + I_ORD, edge_src, edge_attr,
                                            wsU + U_WBUF, ws, W2_0e, W2_1o, outp);
}

// Round 6
// 167.201 us; speedup vs baseline: 25.6554x; 1.1942x over previous
//
#include <hip/hip_runtime.h>

typedef unsigned int uint32;
typedef unsigned short ushrt;
typedef __attribute__((ext_vector_type(4))) float f32x4;
typedef __attribute__((ext_vector_type(8))) _Float16 halfx8;
typedef __attribute__((ext_vector_type(4))) uint32 uint32x4;

#define N_NODES 10000
#define N_EDGES 320000

// scales
#define SC_W1      0.17677669529663687f   // 1/sqrt(32)
#define SC_MLP1    0.35355339059327373f   // 1/sqrt(8)
#define SC_MLP2    0.125f                 // 1/sqrt(64)
#define INV_SQRT3  0.5773502691896258f
#define COS_MIX    0.9238795325112867f    // cos(pi/8)
#define SIN_CONV   0.04783542904563623f   // sin(pi/8) / sqrt(64)

// ws layout
#define WS_FEATP 0        // [N][128] floats, planar: f0 | f1x | f1y | f1z
// int indices (on (int*)ws)
#define I_CNT    1280000  // [N+1]
#define I_OFF    1290016  // [N+1]  (mutated by scatter; gather uses off-cnt)
#define I_ORD    1300032  // [E]
#define I_ESRC   1620032  // [E] ushorts (160000 ints)
// uint indices (on (uint*)ws)
#define U_WF     1780032  // 28 frags x 64 lanes x 4 uints
#define U_WBUF   1787200  // [E][64] packed bf16 pairs, CSR-position order

__device__ __forceinline__ uint32 f2bf(float x) {
    uint32 u = __float_as_uint(x);
    return (u + 0x7fffu + ((u >> 16) & 1u)) >> 16;
}
__device__ __forceinline__ uint32 pack_bf2(float a, float b) {
    return f2bf(a) | (f2bf(b) << 16);
}
__device__ __forceinline__ uint32 packh2(float a, float b) {
    _Float16 ha = (_Float16)a, hb = (_Float16)b;
    return (uint32)__builtin_bit_cast(unsigned short, ha) |
           ((uint32)__builtin_bit_cast(unsigned short, hb) << 16);
}
__device__ __forceinline__ unsigned short h16(float x) {
    _Float16 h = (_Float16)x;
    return __builtin_bit_cast(unsigned short, h);
}
__device__ __forceinline__ float gelu_fast(float x) {
    float x2 = x * x;
    float z = x * __builtin_fmaf(0.03567740814f, x2, 0.7978845608f);
    float E = __builtin_amdgcn_exp2f(z * -2.885390082f);
    return x * __builtin_amdgcn_rcpf(1.0f + E);
}

// ================= K1: node_transform | csr_count | prep_frags ====
#define K1_NODE_BLOCKS 2500
#define K1_CNT_BLOCKS  1250
#define K1_PREP_BLOCKS 7
__global__ __launch_bounds__(256) void k1_fused(
        const float* __restrict__ x,
        const float* __restrict__ W1_0e, const float* __restrict__ W1_1o,
        const int* __restrict__ edge_dst, int* __restrict__ cnt,
        const float* __restrict__ Wm1, const float* __restrict__ Wm2,
        const float* __restrict__ Wp00, const float* __restrict__ Wp01,
        const float* __restrict__ Wp10, const float* __restrict__ Wp11,
        uint32* __restrict__ wf,
        float* __restrict__ featp, float* __restrict__ out) {
    int b = blockIdx.x;
    if (b < K1_NODE_BLOCKS) {
        __shared__ float xrow[4][128];
        int wv = threadIdx.x >> 6, lane = threadIdx.x & 63;
        int node = b * 4 + wv;
        float2 v = *(const float2*)(x + (size_t)node * 128 + lane * 2);
        xrow[wv][lane * 2]     = v.x;
        xrow[wv][lane * 2 + 1] = v.y;
        __syncthreads();
        const float* sx = xrow[wv];
        int w = lane;
        float f0 = 0.f, f1x = 0.f, f1y = 0.f, f1z = 0.f;
#pragma unroll
        for (int u = 0; u < 32; ++u) {
            float w0 = W1_0e[u * 64 + w];
            float w1 = W1_1o[u * 64 + w];
            f0  += sx[u] * w0;
            f1x += sx[32 + u * 3 + 0] * w1;
            f1y += sx[32 + u * 3 + 1] * w1;
            f1z += sx[32 + u * 3 + 2] * w1;
        }
        f0 *= SC_W1; f1x *= SC_W1; f1y *= SC_W1; f1z *= SC_W1;
        if (w < 32) {
            // planar feat table
            featp[node * 128 + w]      = f0;
            featp[node * 128 + 32 + w] = f1x;
            featp[node * 128 + 64 + w] = f1y;
            featp[node * 128 + 96 + w] = f1z;
        } else {
            // prefill output with self-mix term
            int ww = w - 32;
            out[node * 128 + ww] = COS_MIX * f0;
            out[node * 128 + 32 + ww * 3 + 0] = COS_MIX * f1x;
            out[node * 128 + 32 + ww * 3 + 1] = COS_MIX * f1y;
            out[node * 128 + 32 + ww * 3 + 2] = COS_MIX * f1z;
        }
    } else if (b < K1_NODE_BLOCKS + K1_CNT_BLOCKS) {
        int e = (b - K1_NODE_BLOCKS) * 256 + threadIdx.x;
        atomicAdd(&cnt[edge_dst[e]], 1);
    } else {
        int gid = (b - K1_NODE_BLOCKS - K1_CNT_BLOCKS) * 256 + threadIdx.x;
        int f = gid >> 6, lane = gid & 63;
        int kq = (lane >> 4) * 8;
        int c15 = lane & 15;
        float vals[8];
        if (f < 4) {
            int c = 16 * f + c15;
#pragma unroll
            for (int j = 0; j < 8; ++j) { int k = kq + j; vals[j] = (k < 8) ? Wm1[k * 64 + c] : 0.f; }
        } else if (f < 12) {
            int idx = f - 4, nt = idx >> 1, ks = idx & 1;
            int c = 16 * nt + c15;
#pragma unroll
            for (int j = 0; j < 8; ++j) { int k = 32 * ks + kq + j; vals[j] = Wm2[k * 64 + c]; }
        } else {
            int idx = f - 12, nt = idx >> 1, ks = idx & 1;
            int c = 16 * nt + c15;
            int u = c & 31, m = c >> 5;
            const float* W = (m == 0) ? Wp00 : (m == 1) ? Wp01 : (m == 2) ? Wp10 : Wp11;
            float sc = (m == 3) ? 0.125f * INV_SQRT3 : 0.125f;
#pragma unroll
            for (int j = 0; j < 8; ++j) { int k = 32 * ks + kq + j; vals[j] = W[k * 32 + u] * sc; }
        }
        uint32* o = wf + f * 256 + lane * 4;
#pragma unroll
        for (int w = 0; w < 4; ++w) o[w] = packh2(vals[2 * w], vals[2 * w + 1]);
    }
}

// ================= K2: csr_scan (single block) =================
__global__ __launch_bounds__(256) void csr_scan(const int* __restrict__ cnt,
                                                int* __restrict__ off) {
    __shared__ int partial[256];
    int t = threadIdx.x;
    const int CHUNK = 40;
    int base = t * CHUNK;
    int s = 0;
#pragma unroll
    for (int j = 0; j < CHUNK; ++j) {
        int idx = base + j;
        s += (idx < N_NODES) ? cnt[idx] : 0;
    }
    partial[t] = s;
    __syncthreads();
    for (int o = 1; o < 256; o <<= 1) {
        int v = partial[t];
        int add = (t >= o) ? partial[t - o] : 0;
        __syncthreads();
        partial[t] = v + add;
        __syncthreads();
    }
    int run = (t > 0) ? partial[t - 1] : 0;
    for (int j = 0; j < CHUNK; ++j) {
        int idx = base + j;
        if (idx < N_NODES) {
            off[idx] = run;
            run += cnt[idx];
        }
    }
    if (t == 255) off[N_NODES] = run;
}

// ================= K3: csr_scatter (mutates off; gather uses off-cnt) ========
__global__ __launch_bounds__(256) void csr_scatter(const int* __restrict__ src,
                                                   const int* __restrict__ dst,
                                                   int* __restrict__ off,
                                                   int* __restrict__ ord,
                                                   ushrt* __restrict__ esrc) {
    int e = blockIdx.x * 256 + threadIdx.x;   // grid 1250 exact
    int pos = atomicAdd(&off[dst[e]], 1);
    ord[pos] = e;
    esrc[pos] = (ushrt)src[e];
}

// ================= K4: edge_mlp in CSR order (MFMA) =================
#define MLP_BLOCKS 1250
__global__ __launch_bounds__(256) void edge_mlp(const float* __restrict__ edge_scalar,
                                                const float* __restrict__ edge_attr,
                                                const int* __restrict__ ord,
                                                const uint32* __restrict__ wf,
                                                uint32* __restrict__ wbuf) {
    __shared__ unsigned short sh[4][1024];
    __shared__ float eaxs[4][16];
    int lane = threadIdx.x & 63;
    int wvq = threadIdx.x >> 6;
    int wave_id = blockIdx.x * 4 + wvq;

    int kq = (lane >> 4) * 8;
    int r15 = lane & 15;

    const uint32x4* wfp = (const uint32x4*)wf;
    halfx8 wb1[4], wb2[4][2], wbp[8][2];
#pragma unroll
    for (int nt = 0; nt < 4; ++nt)
        wb1[nt] = __builtin_bit_cast(halfx8, wfp[nt * 64 + lane]);
#pragma unroll
    for (int nt = 0; nt < 4; ++nt)
#pragma unroll
        for (int ks = 0; ks < 2; ++ks)
            wb2[nt][ks] = __builtin_bit_cast(halfx8, wfp[(4 + nt * 2 + ks) * 64 + lane]);
#pragma unroll
    for (int nt = 0; nt < 8; ++nt)
#pragma unroll
        for (int ks = 0; ks < 2; ++ks)
            wbp[nt][ks] = __builtin_bit_cast(halfx8, wfp[(12 + nt * 2 + ks) * 64 + lane]);

    const f32x4 z4 = {0.f, 0.f, 0.f, 0.f};
    unsigned short* shw = sh[wvq];

    for (int g = wave_id; g < N_EDGES / 16; g += MLP_BLOCKS * 4) {
        int p0 = g * 16;

        halfx8 a0 = (halfx8)0;
        if (lane < 16) {
            int e = ord[p0 + lane];
            const float* esp = edge_scalar + (size_t)e * 8;
            float4 p = *(const float4*)esp;
            float4 q = *(const float4*)(esp + 4);
            a0[0] = (_Float16)p.x; a0[1] = (_Float16)p.y;
            a0[2] = (_Float16)p.z; a0[3] = (_Float16)p.w;
            a0[4] = (_Float16)q.x; a0[5] = (_Float16)q.y;
            a0[6] = (_Float16)q.z; a0[7] = (_Float16)q.w;
            eaxs[wvq][lane] = edge_attr[(size_t)e * 4];   // ea.x for this row
        }

        f32x4 acc1[4];
#pragma unroll
        for (int nt = 0; nt < 4; ++nt)
            acc1[nt] = __builtin_amdgcn_mfma_f32_16x16x32_f16(a0, wb1[nt], z4, 0, 0, 0);
#pragma unroll
        for (int nt = 0; nt < 4; ++nt)
#pragma unroll
            for (int i = 0; i < 4; ++i) {
                float gv = gelu_fast(acc1[nt][i] * SC_MLP1);
                int rr = (lane >> 4) * 4 + i;
                int ix = rr * 64 + 16 * nt + r15;
                shw[ix ^ ((rr & 7) << 3)] = h16(gv);
            }
        halfx8 a1[2];
#pragma unroll
        for (int ks = 0; ks < 2; ++ks) {
            int ix = r15 * 64 + 32 * ks + kq;
            a1[ks] = __builtin_bit_cast(halfx8,
                       *(const uint32x4*)&shw[ix ^ ((r15 & 7) << 3)]);
        }

        f32x4 acc2[4];
#pragma unroll
        for (int nt = 0; nt < 4; ++nt) {
            acc2[nt] = __builtin_amdgcn_mfma_f32_16x16x32_f16(a1[0], wb2[nt][0], z4, 0, 0, 0);
            acc2[nt] = __builtin_amdgcn_mfma_f32_16x16x32_f16(a1[1], wb2[nt][1], acc2[nt], 0, 0, 0);
        }
#pragma unroll
        for (int nt = 0; nt < 4; ++nt)
#pragma unroll
            for (int i = 0; i < 4; ++i) {
                float gv = gelu_fast(acc2[nt][i] * SC_MLP2);
                int rr = (lane >> 4) * 4 + i;
                int ix = rr * 64 + 16 * nt + r15;
                shw[ix ^ ((rr & 7) << 3)] = h16(gv);
            }
        halfx8 a2[2];
#pragma unroll
        for (int ks = 0; ks < 2; ++ks) {
            int ix = r15 * 64 + 32 * ks + kq;
            a2[ks] = __builtin_bit_cast(halfx8,
                       *(const uint32x4*)&shw[ix ^ ((r15 & 7) << 3)]);
        }

        f32x4 accp[8];
#pragma unroll
        for (int nt = 0; nt < 8; ++nt) {
            accp[nt] = __builtin_amdgcn_mfma_f32_16x16x32_f16(a2[0], wbp[nt][0], z4, 0, 0, 0);
            accp[nt] = __builtin_amdgcn_mfma_f32_16x16x32_f16(a2[1], wbp[nt][1], accp[nt], 0, 0, 0);
        }
        // fold ea.x into w00/w10; store rows at CSR positions (contiguous)
#pragma unroll
        for (int i = 0; i < 4; ++i) {
            int rr = (lane >> 4) * 4 + i;
            float eax = eaxs[wvq][rr];
            size_t base = ((size_t)(p0 + rr)) * 64 + r15;
            wbuf[base]      = pack_bf2(accp[0][i] * eax, accp[2][i]);
            wbuf[base + 16] = pack_bf2(accp[1][i] * eax, accp[3][i]);
            wbuf[base + 32] = pack_bf2(accp[4][i] * eax, accp[6][i]);
            wbuf[base + 48] = pack_bf2(accp[5][i] * eax, accp[7][i]);
        }
    }
}

// ================= K5: gather (CSR streams + 4-deep pipeline) =================
__global__ __launch_bounds__(256) void gather(const int* __restrict__ off,
                                              const int* __restrict__ cnt,
                                              const int* __restrict__ ord,
                                              const ushrt* __restrict__ esrc,
                                              const float* __restrict__ edge_attr,
                                              const uint32* __restrict__ wbuf,
                                              const float* __restrict__ featp,
                                              const float* __restrict__ W2_0e,
                                              const float* __restrict__ W2_1o,
                                              float* __restrict__ out) {
    int wv = threadIdx.x >> 6;
    int lane = threadIdx.x & 63;
    int node = blockIdx.x * 4 + wv;
    int u = lane & 31;
    int half = lane >> 5;

    int end = __builtin_amdgcn_readfirstlane(off[node]);     // off mutated by scatter
    int beg = end - __builtin_amdgcn_readfirstlane(cnt[node]);

    float a0 = 0.f, a1x = 0.f, a1y = 0.f, a1z = 0.f;

    for (int i0 = beg; i0 < end; i0 += 64) {
        int nn = end - i0;
        if (nn > 64) nn = 64;
        int idx = i0 + ((lane < nn) ? lane : 0);
        int ev = ord[idx];
        int sv = (int)esrc[idx];
        for (int j0 = 0; j0 < nn; j0 += 4) {
            uint32 wv_[4];
            float fa_[4], fb_[4], fc_[4], ey_[4], ez_[4], ew_[4];
#pragma unroll
            for (int t = 0; t < 4; ++t) {
                int j = j0 + t;
                int jc = (j < nn) ? j : nn - 1;
                int e = __builtin_amdgcn_readlane(ev, jc);     // SGPR
                int s = __builtin_amdgcn_readlane(sv, jc);     // SGPR
                const float* ep = edge_attr + (size_t)e * 4;
                ey_[t] = ep[1]; ez_[t] = ep[2]; ew_[t] = ep[3];
                uint32 wl = wbuf[(size_t)(i0 + jc) * 64 + lane];   // linear stream
                wv_[t] = (j < nn) ? wl : 0u;                       // gate tail
                const float* fp = featp + s * 128;
                fa_[t] = fp[u + half * 32];
                fb_[t] = fp[64 + u];
                fc_[t] = fp[96 + u];
            }
#pragma unroll
            for (int t = 0; t < 4; ++t) {
                float wa = __uint_as_float(wv_[t] << 16);
                float wb = __uint_as_float(wv_[t] & 0xffff0000u);
                float va = half ? ey_[t] : 1.0f;
                float vb = half ? ez_[t] : 0.0f;
                float vc = half ? ew_[t] : 0.0f;
                float dot = fa_[t] * va + fb_[t] * vb + fc_[t] * vc;
                float w0s = half ? wb : wa;
                a0 += w0s * dot;
                float m  = half ? wa : wb * fa_[t];
                float vx = half ? fa_[t] : ey_[t];
                float vy = half ? fb_[t] : ez_[t];
                float vz = half ? fc_[t] : ew_[t];
                a1x += m * vx; a1y += m * vy; a1z += m * vz;
            }
        }
    }

    __shared__ float red[4][256];
    float* r = red[wv];
    int c = (half << 5) + u;
    r[c] = a0;
    int b = 64 + c * 3;
    r[b] = a1x; r[b + 1] = a1y; r[b + 2] = a1z;
    __syncthreads();

    if (half == 0) {
        float acc = 0.f;
#pragma unroll 8
        for (int w = 0; w < 64; ++w) acc += r[w] * W2_0e[w * 32 + u];
        int o = node * 128 + u;
        out[o] = out[o] + SIN_CONV * acc;         // prefilled with COS_MIX*self
    } else {
        float c0 = 0.f, c1 = 0.f, c2 = 0.f;
#pragma unroll 8
        for (int w = 0; w < 64; ++w) {
            float bw = W2_1o[w * 32 + u];
            c0 += r[64 + w * 3 + 0] * bw;
            c1 += r[64 + w * 3 + 1] * bw;
            c2 += r[64 + w * 3 + 2] * bw;
        }
        int o = node * 128 + 32 + u * 3;
        out[o + 0] = out[o + 0] + SIN_CONV * c0;
        out[o + 1] = out[o + 1] + SIN_CONV * c1;
        out[o + 2] = out[o + 2] + SIN_CONV * c2;
    }
}

extern "C" void kernel_launch(void* const* d_in, const int* in_sizes, int n_in,
                              void* d_out, int out_size, void* d_ws, size_t ws_size,
                              hipStream_t stream) {
    const float* node_input  = (const float*)d_in[0];
    const float* edge_attr   = (const float*)d_in[1];
    const float* edge_scalar = (const float*)d_in[2];
    const float* W1_0e       = (const float*)d_in[3];
    const float* W1_1o       = (const float*)d_in[4];
    const float* W_mlp1      = (const float*)d_in[5];
    const float* W_mlp2      = (const float*)d_in[6];
    const float* Wp00        = (const float*)d_in[7];
    const float* Wp01        = (const float*)d_in[8];
    const float* Wp10        = (const float*)d_in[9];
    const float* Wp11        = (const float*)d_in[10];
    const float* W2_0e       = (const float*)d_in[11];
    const float* W2_1o       = (const float*)d_in[12];
    const int*   edge_src    = (const int*)d_in[13];
    const int*   edge_dst    = (const int*)d_in[14];
    float* ws   = (float*)d_ws;
    int*   wsI  = (int*)d_ws;
    uint32* wsU = (uint32*)d_ws;
    ushrt* esrcp = (ushrt*)(wsI + I_ESRC);
    float* outp = (float*)d_out;

    hipMemsetAsync(wsI + I_CNT, 0, (N_NODES + 1) * sizeof(int), stream);

    k1_fused<<<K1_NODE_BLOCKS + K1_CNT_BLOCKS + K1_PREP_BLOCKS, 256, 0, stream>>>(
        node_input, W1_0e, W1_1o, edge_dst, wsI + I_CNT,
        W_mlp1, W_mlp2, Wp00, Wp01, Wp10, Wp11, wsU + U_WF, ws + WS_FEATP, outp);
    csr_scan<<<1, 256, 0, stream>>>(wsI + I_CNT, wsI + I_OFF);
    csr_scatter<<<1250, 256, 0, stream>>>(edge_src, edge_dst, wsI + I_OFF,
                                          wsI + I_ORD, esrcp);
    edge_mlp<<<MLP_BLOCKS, 256, 0, stream>>>(edge_scalar, edge_attr, wsI + I_ORD,
                                             wsU + U_WF, wsU + U_WBUF);
    gather<<<N_NODES / 4, 256, 0, stream>>>(wsI + I_OFF, wsI + I_CNT, wsI + I_ORD, esrcp,
                                            edge_attr, wsU + U_WBUF, ws + WS_FEATP,
                                            W2_0e, W2_1o, outp);
}